// Round 5
// baseline (92.833 us; speedup 1.0000x reference)
//
#include <hip/hip_runtime.h>
#include <math.h>

#define L2PI 1.8378770664093454835606594728112
#define LN2  0.69314718055994530941723212145818
#define MAGIC 0x7E57C0DE

// ---------------------------------------------------------------------------
// Lane-parallel Gaussian potential (fp32) over (F = first state(4),
// L = last state(4), B = class-bias means(4)).  16 lanes per potential;
// lane (i,j) holds element (i,j) of each 4x4 J block; h vectors replicated
// over rows (lane (i,j) holds h[j]); g/dm/de replicated.
// log psi = g + h.x - 0.5 x'Jx, det product carried in (dm, de).
//
// compose(): LDS-staged rows (~10 ds_write_b32 + ~18 ds_read_b128 in 3
// batched lgkmcnt(0) waits) — verified round 4, bit-identical to shuffles.
// Structure: fused single kernel (verified round 0): 32 blocks produce,
// block 0 consumes after flag spin — avoids the second dispatch boundary.
// ---------------------------------------------------------------------------
struct LP {
    float jFF, jFL, jFB, jLL, jLB, jBB;
    float hF, hL, hB, g, dm, de;
};

struct Cn { float qa, qb, qc, wa, wb, ri, Cstep; };

__device__ __forceinline__ float shf(float v, int s) { return __shfl(v, s, 64); }
__device__ __forceinline__ float sx (float v, int m) { return __shfl_xor(v, m, 64); }

#define LGKM0() do { \
    asm volatile("s_waitcnt lgkmcnt(0)" ::: "memory"); \
    __builtin_amdgcn_sched_barrier(0); \
} while (0)

// per-group LDS scratch layout (floats); stride 152 => group bank offsets
// {0,24,16,8} mod 32: every row access is at most 2-way bank aliased (free).
#define OFF_S   0
#define OFF_SI  16
#define OFF_F1  32
#define OFF_F2T 48
#define OFF_MT  64
#define OFF_A1  80
#define OFF_C1T 96
#define OFF_B2T 112
#define OFF_V4  128
#define OFF_HM  132
#define GSTRIDE 152

__device__ __forceinline__ float4 ld4(const float* p) {
    return *(const float4*)p;
}
__device__ __forceinline__ float dot4(float4 a, float4 b) {
    float s = a.x * b.x;
    s = fmaf(a.y, b.y, s);
    s = fmaf(a.z, b.z, s);
    s = fmaf(a.w, b.w, s);
    return s;
}

// Single-step potential: N(z'; F z, Qs) * prod_k N(y_k; b_k + z'_{h_k}, r)
__device__ __forceinline__ LP init_lane(float x0, float x1, const Cn& C, int i, int j) {
    LP P;
    float v = 0.0f;
    if (i == j) v = (i < 2) ? C.qa : C.qc;
    if ((i ^ j) == 2) v = C.wa;
    P.jFF = v;
    v = 0.0f;
    if (j == (i & 1))     v = (i < 2) ? -C.qa : -C.wa;
    if (j == (i & 1) + 2) v = (i < 2) ? -C.qb : -C.wb;
    P.jFL = v;
    P.jFB = 0.0f;
    v = 0.0f;
    if (i == j) v = ((i < 2) ? C.qa : C.qc) + (((i & 1) == 0) ? 2.0f*C.ri : 0.0f);
    if ((i ^ j) == 2) v = C.qb;
    P.jLL = v;
    P.jLB = (((i == 0) && (j < 2)) || ((i == 2) && (j >= 2))) ? C.ri : 0.0f;
    P.jBB = (i == j) ? C.ri : 0.0f;
    P.hF = 0.0f;
    P.hL = ((j & 1) == 0) ? C.ri * (x0 + x1) : 0.0f;
    P.hB = C.ri * ((j & 1) ? x1 : x0);
    P.g  = -C.ri * (x0*x0 + x1*x1) + C.Cstep;
    P.dm = 1.0f; P.de = 0.0f;
    return P;
}

// Compose P1 (earlier) o P2 (later), marginalizing the shared middle state.
// LDS-staged: gl points at this 16-lane group's private scratch region.
// Only same-wave LDS traffic -> lgkmcnt(0) suffices (no barrier).
__device__ __forceinline__ LP compose(const LP& P1, const LP& P2, float* gl, int i, int j) {
    float hm = P1.hL + P2.hF;      // lane holds hm[j]
    float Mb = P1.jLB + P2.jFB;    // M[i][j]
    float S  = P1.jLL + P2.jFF;    // S[i][j] (symmetric)
    float dm = P1.dm * P2.dm;
    float de = P1.de + P2.de;
    { int ex; dm = frexpf(dm, &ex); de += (float)ex; }
    const int ij = 4*i + j, ji = 4*j + i;

    // ---- round 1: stage shared operands ----
    gl[OFF_S   + ij] = S;
    gl[OFF_F1  + ij] = P1.jFL;      // F1 row-major
    gl[OFF_F2T + ji] = P2.jFL;      // F2 transposed
    gl[OFF_MT  + ji] = Mb;          // M  transposed
    if (i == 0) gl[OFF_HM + j] = hm;
    LGKM0();

    // minor rows (exclude row j), cols (exclude col i) -- same as shuffle ver.
    const int r0 = (j == 0) ? 1 : 0;
    const int r1 = (j <= 1) ? 2 : 1;
    const int r2 = (j <= 2) ? 3 : 2;
    float4 R0 = ld4(gl + OFF_S + 4*r0);
    float4 R1 = ld4(gl + OFF_S + 4*r1);
    float4 R2 = ld4(gl + OFF_S + 4*r2);
    float4 RJ = ld4(gl + OFF_S + 4*j);
    float4 f1r4 = ld4(gl + OFF_F1  + 4*i);   // F1[i,:]
    float4 f1T4 = ld4(gl + OFF_F1  + 4*j);   // F1[j,:]
    float4 f2c4 = ld4(gl + OFF_F2T + 4*j);   // F2[:,j]
    float4 f2T4 = ld4(gl + OFF_F2T + 4*i);   // F2[:,i]
    float4 mc4  = ld4(gl + OFF_MT  + 4*j);   // M[:,j]
    float4 mT4  = ld4(gl + OFF_MT  + 4*i);   // M[:,i]
    float4 hm4  = ld4(gl + OFF_HM);

    const bool i0 = (i == 0), i1 = (i <= 1), i2 = (i <= 2);
    float m00 = i0 ? R0.y : R0.x, m01 = i1 ? R0.z : R0.y, m02 = i2 ? R0.w : R0.z;
    float m10 = i0 ? R1.y : R1.x, m11 = i1 ? R1.z : R1.y, m12 = i2 ? R1.w : R1.z;
    float m20 = i0 ? R2.y : R2.x, m21 = i1 ? R2.z : R2.y, m22 = i2 ? R2.w : R2.z;
    float d0 = fmaf(m11, m22, -m12*m21);
    float d1 = fmaf(m10, m22, -m12*m20);
    float d2 = fmaf(m10, m21, -m11*m20);
    float det3 = m00*d0 - m01*d1 + m02*d2;
    float adj = (((i + j) & 1) ? -det3 : det3);
    float sji = (i < 2) ? (i0 ? RJ.x : RJ.y) : ((i == 2) ? RJ.z : RJ.w);
    float t = sji * adj;
    t += sx(t, 4); t += sx(t, 8);           // det, replicated over group
    float det = t;
    dm *= det; { int ex; dm = frexpf(dm, &ex); de += (float)ex; }
    float Sio = adj * (1.0f / det);         // Si[i][j] (symmetric)

    // ---- round 2: stage Si ----
    gl[OFF_SI + ij] = Sio;
    LGKM0();
    float4 sr4 = ld4(gl + OFF_SI + 4*i);    // Si[i,:]
    float4 sc4 = ld4(gl + OFF_SI + 4*j);    // Si[:,j] (= row j, symmetric)

    float A1  = dot4(f1r4, sc4);            // (F1*Si)[i,j]
    float C1  = dot4(sr4,  mc4);            // (Si*M)[i,j]
    float B2  = dot4(sr4,  f2c4);           // (Si*F2)[i,j]
    float v4i = dot4(sr4,  hm4);            // (Si*hm)[i]

    // ---- round 3: stage products ----
    gl[OFF_A1  + ij] = A1;
    gl[OFF_C1T + ji] = C1;
    gl[OFF_B2T + ji] = B2;
    if (i == j) gl[OFF_V4 + i] = v4i;
    LGKM0();
    float4 a1r4 = ld4(gl + OFF_A1  + 4*i);  // A1[i,:]
    float4 a1j4 = ld4(gl + OFF_A1  + 4*j);  // A1[j,:]
    float4 c1c4 = ld4(gl + OFF_C1T + 4*j);  // C1[:,j]
    float4 b2c4 = ld4(gl + OFF_B2T + 4*j);  // B2[:,j]
    float4 v44  = ld4(gl + OFF_V4);

    LP R;
    R.jFF = P1.jFF - dot4(a1r4, f1T4);
    R.jFL = -dot4(a1r4, f2c4);
    R.jFB = P1.jFB - dot4(a1r4, mc4);
    R.jLL = P2.jLL - dot4(f2T4, b2c4);
    R.jLB = P2.jLB - dot4(f2T4, c1c4);
    R.jBB = P1.jBB + P2.jBB - dot4(mT4, c1c4);
    R.hF  = P1.hF - dot4(a1j4, hm4);
    R.hL  = P2.hL - dot4(f2c4, v44);
    R.hB  = P1.hB + P2.hB - dot4(mc4, v44);
    R.g   = P1.g + P2.g + 2.0f*(float)L2PI + 0.5f*dot4(hm4, v44);
    R.dm = dm; R.de = de;
    return R;
}

__device__ __forceinline__ LP fetchx(const LP& P, int m) {
    LP O;
    O.jFF = sx(P.jFF,m); O.jFL = sx(P.jFL,m); O.jFB = sx(P.jFB,m);
    O.jLL = sx(P.jLL,m); O.jLB = sx(P.jLB,m); O.jBB = sx(P.jBB,m);
    O.hF  = sx(P.hF,m);  O.hL  = sx(P.hL,m);  O.hB  = sx(P.hB,m);
    O.g   = sx(P.g,m);   O.dm  = sx(P.dm,m);  O.de  = sx(P.de,m);
    return O;
}
__device__ __forceinline__ LP csel(bool up, const LP& O, const LP& P) {
    LP A;
    A.jFF = up?O.jFF:P.jFF; A.jFL = up?O.jFL:P.jFL; A.jFB = up?O.jFB:P.jFB;
    A.jLL = up?O.jLL:P.jLL; A.jLB = up?O.jLB:P.jLB; A.jBB = up?O.jBB:P.jBB;
    A.hF  = up?O.hF :P.hF;  A.hL  = up?O.hL :P.hL;  A.hB  = up?O.hB :P.hB;
    A.g   = up?O.g  :P.g;   A.dm  = up?O.dm :P.dm;  A.de  = up?O.de :P.de;
    return A;
}
__device__ __forceinline__ void pot_store(float* p, const LP& P) {
    p[0]=P.jFF; p[1]=P.jFL; p[2]=P.jFB; p[3]=P.jLL; p[4]=P.jLB; p[5]=P.jBB;
    p[6]=P.hF;  p[7]=P.hL;  p[8]=P.hB;  p[9]=P.g;   p[10]=P.dm; p[11]=P.de;
}
__device__ __forceinline__ LP pot_load(const float* p) {
    LP P;
    P.jFF=p[0]; P.jFL=p[1]; P.jFB=p[2]; P.jLL=p[3]; P.jLB=p[4]; P.jBB=p[5];
    P.hF=p[6];  P.hL=p[7];  P.hB=p[8];  P.g=p[9];   P.dm=p[10]; P.de=p[11];
    return P;
}
__device__ __forceinline__ float cload(const float* p) {
    return __hip_atomic_load(p, __ATOMIC_RELAXED, __HIP_MEMORY_SCOPE_AGENT);
}
__device__ __forceinline__ LP pot_load_coh(const float* p) {
    LP P;
    P.jFF=cload(p+0); P.jFL=cload(p+1); P.jFB=cload(p+2);
    P.jLL=cload(p+3); P.jLB=cload(p+4); P.jBB=cload(p+5);
    P.hF=cload(p+6);  P.hL=cload(p+7);  P.hB=cload(p+8);
    P.g=cload(p+9);   P.dm=cload(p+10); P.de=cload(p+11);
    return P;
}

// ---------- Fused kernel: 32 blocks x 512 threads (8 waves).
// Produce: each block folds 64 steps (32 groups x 2; depth 1+2+3=6) -> ws+flag.
// Consume (block 0): spin, 32 groups load 1 pot each, depth 2+3=5, finalize,
// expand.  Total sequential composes: 11. ----------
__global__ __launch_bounds__(512)
void hmm_fused(const float* __restrict__ track,
               const float* __restrict__ bias_scales,
               const float* __restrict__ obs_noise_p,
               const float* __restrict__ trans_noise_p,
               float* __restrict__ ws,
               float* __restrict__ out)
{
    __shared__ float pool[2][8][16][13];
    __shared__ __align__(16) float cbuf[32 * GSTRIDE];
    __shared__ float sTi[8][8];
    __shared__ float sA[4];
    __shared__ float sLL;
    const int tid = (int)threadIdx.x;
    const int l = tid & 63, w = tid >> 6;
    const int i = (l >> 2) & 3, j = l & 3, gb = l & 48, g = (l >> 4) & 3;
    const int gid = w * 4 + g;            // group 0..31
    float* gl = &cbuf[(size_t)gid * GSTRIDE];
    const int bid = (int)blockIdx.x;

    const double sg2d = (double)obs_noise_p[0] * (double)obs_noise_p[0];
    const double qn2d = (double)trans_noise_p[0] * (double)trans_noise_p[0];
    const double a00 = (double)bias_scales[0];
    const double a01 = (double)bias_scales[1];

    Cn C;
    C.qa = (float)(12.0/qn2d); C.qb = (float)(-6.0/qn2d); C.qc = (float)(4.0/qn2d);
    C.wa = (float)(6.0/qn2d);  C.wb = (float)(-2.0/qn2d);
    C.ri = (float)(32.0/sg2d);
    C.Cstep = (float)(-2.0*log(2.0*M_PI*sg2d/32.0) - 2.0*L2PI
                      - 0.5*(4.0*log(qn2d) - 2.0*log(12.0)));

    int* flags = (int*)(ws + 8192);       // after 32 KB; pots use 24 KB

    // ================= produce phase (all 32 blocks) =================
    {
        const int t0 = (bid * 32 + gid) * 2;
        LP P;
        #pragma unroll 1
        for (int op = 0; op < 6; ++op) {
            LP A, Bp;
            if (op == 0) {
                A  = init_lane(track[2*t0+0], track[2*t0+1], C, i, j);
                Bp = init_lane(track[2*t0+2], track[2*t0+3], C, i, j);
            } else if (op < 3) {
                const int m = 16 << (op - 1);
                LP O = fetchx(P, m);
                const bool up = (l & m) != 0;
                A  = csel(up, O, P);
                Bp = csel(up, P, O);
            } else {
                const int s = 1 << (op - 3);
                const int buf = (op - 3) & 1;
                if (l < 16) pot_store(&pool[buf][w][l][0], P);
                __syncthreads();
                LP O = pot_load(&pool[buf][w ^ s][l & 15][0]);
                const bool up = (w & s) != 0;
                A  = csel(up, O, P);
                Bp = csel(up, P, O);
            }
            P = compose(A, Bp, gl, i, j);
        }
        if (w == 0 && l < 16)
            pot_store(ws + ((size_t)bid * 16 + l) * 12, P);
        __threadfence();
        __syncthreads();
        if (tid == 0)
            __hip_atomic_store(&flags[bid * 32], MAGIC,
                               __ATOMIC_RELEASE, __HIP_MEMORY_SCOPE_AGENT);
    }
    if (bid != 0) return;

    // ================= consume phase (block 0) =================
    if (tid < 32) {
        while (__hip_atomic_load(&flags[tid * 32],
                                 __ATOMIC_ACQUIRE, __HIP_MEMORY_SCOPE_AGENT) != MAGIC)
            __builtin_amdgcn_s_sleep(2);
    }
    __syncthreads();
    __threadfence();

    LP P = pot_load_coh(ws + ((size_t)gid * 16 + (l & 15)) * 12);
    #pragma unroll 1
    for (int op = 0; op < 5; ++op) {
        LP A, Bp;
        if (op < 2) {
            const int m = 16 << op;
            LP O = fetchx(P, m);
            const bool up = (l & m) != 0;
            A  = csel(up, O, P);
            Bp = csel(up, P, O);
        } else {
            const int s = 1 << (op - 2);
            const int buf = (op - 2) & 1;
            if (l < 16) pot_store(&pool[buf][w][l][0], P);
            __syncthreads();
            LP O = pot_load(&pool[buf][w ^ s][l & 15][0]);
            const bool up = (w & s) != 0;
            A  = csel(up, O, P);
            Bp = csel(up, P, O);
        }
        P = compose(A, Bp, gl, i, j);
    }

    // ---------- final stage on wave 0 ----------
    if (w == 0) {
        const float a0i = (float)((i & 1) ? a01 : a00);
        P.jFF += (i == j) ? 1.0f : 0.0f;
        P.jBB += (i == j) ? 32.0f / a0i : 0.0f;
        P.g   += (float)(-4.0*L2PI + 2.0*log(32.0) - log(a00) - log(a01));
        float dm = P.dm, de = P.de;
        // marginalize z0: adjugate inverse of jFF
        float S = P.jFF;
        const int r0 = (j == 0) ? 1 : 0;
        const int r1 = (j <= 1) ? 2 : 1;
        const int r2 = (j <= 2) ? 3 : 2;
        const int c0 = (i == 0) ? 1 : 0;
        const int c1 = (i <= 1) ? 2 : 1;
        const int c2 = (i <= 2) ? 3 : 2;
        float m00 = shf(S, gb + 4*r0 + c0), m01 = shf(S, gb + 4*r0 + c1), m02 = shf(S, gb + 4*r0 + c2);
        float m10 = shf(S, gb + 4*r1 + c0), m11 = shf(S, gb + 4*r1 + c1), m12 = shf(S, gb + 4*r1 + c2);
        float m20 = shf(S, gb + 4*r2 + c0), m21 = shf(S, gb + 4*r2 + c1), m22 = shf(S, gb + 4*r2 + c2);
        float d0 = fmaf(m11, m22, -m12*m21);
        float d1 = fmaf(m10, m22, -m12*m20);
        float d2 = fmaf(m10, m21, -m11*m20);
        float det3 = m00*d0 - m01*d1 + m02*d2;
        float adj = (((i + j) & 1) ? -det3 : det3);
        float sji = shf(S, gb + 4*j + i);
        float tdet = sji * adj;
        tdet += sx(tdet, 4); tdet += sx(tdet, 8);
        float det = tdet;
        dm *= det; { int ex; dm = frexpf(dm, &ex); de += (float)ex; }
        const float Si = adj * (1.0f / det);
        float sr[4], fr[4], fT[4], bc[4], bT[4], hfc[4];
        #pragma unroll
        for (int r = 0; r < 4; ++r) {
            sr[r]  = shf(Si, gb + 4*i + r);
            fr[r]  = shf(P.jFL, gb + 4*r + i);
            fT[r]  = shf(P.jFL, gb + 4*r + j);
            bc[r]  = shf(P.jFB, gb + 4*r + i);
            bT[r]  = shf(P.jFB, gb + 4*r + j);
            hfc[r] = shf(P.hF, gb + 5*r);
        }
        float YL = 0.0f, YB = 0.0f, yFi = 0.0f;
        #pragma unroll
        for (int r = 0; r < 4; ++r) {
            YL  = fmaf(sr[r], fT[r], YL);
            YB  = fmaf(sr[r], bT[r], YB);
            yFi = fmaf(sr[r], hfc[r], yFi);
        }
        float ylc[4], ybc[4], yfc[4];
        #pragma unroll
        for (int r = 0; r < 4; ++r) {
            ylc[r] = shf(YL, gb + 4*r + j);
            ybc[r] = shf(YB, gb + 4*r + j);
            yfc[r] = shf(yFi, gb + 5*r);
        }
        float s1 = 0.0f, s2 = 0.0f, s3 = 0.0f, sh1 = 0.0f, sh2 = 0.0f, qF = 0.0f;
        #pragma unroll
        for (int r = 0; r < 4; ++r) {
            s1  = fmaf(fr[r], ylc[r], s1);
            s2  = fmaf(fr[r], ybc[r], s2);
            s3  = fmaf(bc[r], ybc[r], s3);
            sh1 = fmaf(fT[r], yfc[r], sh1);
            sh2 = fmaf(bT[r], yfc[r], sh2);
            qF  = fmaf(hfc[r], yfc[r], qF);
        }
        float J8ss = P.jLL - s1;
        float J8sb = P.jLB - s2;
        float J8bb = P.jBB - s3;
        float h8s  = P.hL - sh1;
        float h8b  = P.hB - sh2;
        float g8   = P.g + 2.0f*(float)L2PI + 0.5f*qF;

        // 8x8 stage across all 64 lanes: lane = (I,J)
        const int I = l >> 3, J = l & 7, i4 = I & 3, j4 = J & 3;
        float ss  = shf(J8ss, 4*i4 + j4);
        float sb  = shf(J8sb, 4*i4 + j4);
        float sbT = shf(J8sb, 4*j4 + i4);
        float bb  = shf(J8bb, 4*i4 + j4);
        float A8 = (I < 4) ? ((J < 4) ? ss : sb) : ((J < 4) ? sbT : bb);
        const float J8sav = A8;
        float h8v = (J < 4) ? shf(h8s, j4) : shf(h8b, j4);
        float h8r = (I < 4) ? shf(h8s, i4) : shf(h8b, i4);
        float K8 = (I == J) ? 1.0f : 0.0f;
        #pragma unroll 1
        for (int p = 0; p < 8; ++p) {
            float piv = shf(A8, 9*p);
            dm *= piv; { int ex; dm = frexpf(dm, &ex); de += (float)ex; }
            float ip = 1.0f / piv;
            float Ap = shf(A8, 8*p + J) * ip;
            float Kp = shf(K8, 8*p + J) * ip;
            float f  = shf(A8, 8*I + p);
            bool isp = (I == p);
            A8 = isp ? A8 * ip : fmaf(-f, Ap, A8);
            K8 = isp ? K8 * ip : fmaf(-f, Kp, K8);
        }
        float tq = h8r * K8 * h8v;
        tq += sx(tq,1); tq += sx(tq,2); tq += sx(tq,4);
        tq += sx(tq,8); tq += sx(tq,16); tq += sx(tq,32);

        double ll = (double)g8 + 4.0*L2PI
                    - 0.5*(log((double)dm) + (double)de*LN2) + 0.5*(double)tq;
        const double Td = 2048.0;
        const double c0d = sg2d/a00, c1d = sg2d/a01;
        ll += -31.0*(Td*(L2PI + log(sg2d)) + log((c0d+Td)/c0d))
              -31.0*(Td*(L2PI + log(sg2d)) + log((c1d+Td)/c1d))
              -2.0*Td*log(32.0);

        const float i32 = 1.0f/32.0f, irn = 0.176776695296637f;
        int a = (I >= 4) ? I - 4 : I + 4;
        int b = (J >= 4) ? J - 4 : J + 4;
        float scale = (I >= 4 && J >= 4) ? i32 : (((I >= 4) != (J >= 4)) ? irn : 1.0f);
        sTi[a][b] = J8sav * scale;
        if (l < 4) {
            double a0k = (l & 1) ? a01 : a00;
            sA[l] = (float)(a0k*sg2d/(sg2d + Td*a0k));
        }
        if (l == 0) sLL = (float)ll;
    }
    __syncthreads();

    // ---------- expand 1 + 132x132 outputs ----------
    const float inv32 = 1.0f/32.0f;
    const float invrn = 0.176776695296637f;
    const int total = 1 + 132*132;
    #pragma unroll 1
    for (int idx = tid; idx < total; idx += 512) {
        float v;
        if (idx == 0) {
            v = sLL;
        } else {
            int el = idx - 1;
            int r = el / 132;
            int cc = el - 132*r;
            if (r < 128) {
                int ki = ((r >> 6) << 1) | (r & 1);
                if (cc < 128) {
                    int kj = ((cc >> 6) << 1) | (cc & 1);
                    v = sTi[ki][kj] * inv32;
                    if (ki == kj) {
                        float ia = 1.0f / sA[ki];
                        v -= ia * inv32;
                        if (r == cc) v += ia;
                    }
                } else {
                    v = sTi[ki][cc - 124] * invrn;
                }
            } else {
                if (cc < 128) {
                    int kj = ((cc >> 6) << 1) | (cc & 1);
                    v = sTi[kj][r - 124] * invrn;
                } else {
                    v = sTi[r - 124][cc - 124];
                }
            }
        }
        out[idx] = v;
    }
}

extern "C" void kernel_launch(void* const* d_in, const int* in_sizes, int n_in,
                              void* d_out, int out_size, void* d_ws, size_t ws_size,
                              hipStream_t stream) {
    (void)in_sizes; (void)n_in; (void)out_size; (void)ws_size;
    const float* track       = (const float*)d_in[0];
    const float* bias_scales = (const float*)d_in[1];
    const float* obs_noise   = (const float*)d_in[2];
    const float* trans_noise = (const float*)d_in[3];
    float* out = (float*)d_out;
    float* ws  = (float*)d_ws;   // 24 KB pots + flags at +32 KB (0xAA poison != MAGIC)
    hipLaunchKernelGGL(hmm_fused, dim3(32), dim3(512), 0, stream,
                       track, bias_scales, obs_noise, trans_noise, ws, out);
}

// Round 6
// 88.825 us; speedup vs baseline: 1.0451x; 1.0451x over previous
//
#include <hip/hip_runtime.h>
#include <math.h>

#define L2PI 1.8378770664093454835606594728112
#define LN2  0.69314718055994530941723212145818

// ---------------------------------------------------------------------------
// Lane-parallel Gaussian potential (fp32) over (F = first state(4),
// L = last state(4), B = class-bias means(4)).  16 lanes per potential;
// lane (i,j) holds element (i,j) of each 4x4 J block; h vectors replicated
// over rows (lane (i,j) holds h[j]); g/dm/de replicated.
// log psi = g + h.x - 0.5 x'Jx, det product carried in (dm, de).
//
// Round-6 compose: ONE LDS staging round (5 ds_write + lgkmcnt(0) + 12
// ds_read_b128), then the full 4x4 inverse and every intermediate product
// is computed locally per lane (redundant VALU, which is ~99% idle).
// All fmaf orders match the verified 3-round version -> bit-identical.
// ---------------------------------------------------------------------------
struct LP {
    float jFF, jFL, jFB, jLL, jLB, jBB;
    float hF, hL, hB, g, dm, de;
};

struct Cn { float qa, qb, qc, wa, wb, ri, Cstep; };

__device__ __forceinline__ float shf(float v, int s) { return __shfl(v, s, 64); }
__device__ __forceinline__ float sx (float v, int m) { return __shfl_xor(v, m, 64); }

#define LGKM0() do { \
    asm volatile("s_waitcnt lgkmcnt(0)" ::: "memory"); \
    __builtin_amdgcn_sched_barrier(0); \
} while (0)

// per-group LDS scratch layout (floats); stride 152 => group bank offsets
// {0,24,16,8} mod 32 (proven conflict-free in rounds 4/5).
#define OFF_S   0
#define OFF_F1  16
#define OFF_F2T 32
#define OFF_MT  48
#define OFF_HM  64
#define GSTRIDE 152

__device__ __forceinline__ float4 ld4(const float* p) {
    return *(const float4*)p;
}
// identical accumulation order to the verified versions:
// s = a0*b0 (== fmaf(a0,b0,0)); s = fmaf(a1,b1,s); ...
__device__ __forceinline__ float dot4(float4 a, float4 b) {
    float s = a.x * b.x;
    s = fmaf(a.y, b.y, s);
    s = fmaf(a.z, b.z, s);
    s = fmaf(a.w, b.w, s);
    return s;
}
__device__ __forceinline__ float sel4(float x0, float x1, float x2, float x3, int k) {
    return (k == 0) ? x0 : ((k == 1) ? x1 : ((k == 2) ? x2 : x3));
}

// Full 4x4 adjugate (adjE[a][b] == value the verified kernel computed at lane
// (i=a, j=b): minor rows exclude b, cols exclude a, sign (a+b)&1).
// All indices compile-time after full unroll -> stays in registers.
struct Adj4 { float e[4][4]; };
__device__ __forceinline__ Adj4 adj4(const float4& Ra, const float4& Rb,
                                     const float4& Rc, const float4& Rd) {
    float sS[4][4];
    sS[0][0]=Ra.x; sS[0][1]=Ra.y; sS[0][2]=Ra.z; sS[0][3]=Ra.w;
    sS[1][0]=Rb.x; sS[1][1]=Rb.y; sS[1][2]=Rb.z; sS[1][3]=Rb.w;
    sS[2][0]=Rc.x; sS[2][1]=Rc.y; sS[2][2]=Rc.z; sS[2][3]=Rc.w;
    sS[3][0]=Rd.x; sS[3][1]=Rd.y; sS[3][2]=Rd.z; sS[3][3]=Rd.w;
    Adj4 A;
    #pragma unroll
    for (int a = 0; a < 4; ++a) {
        const int c0 = (a == 0) ? 1 : 0;
        const int c1 = (a <= 1) ? 2 : 1;
        const int c2 = (a <= 2) ? 3 : 2;
        #pragma unroll
        for (int b = 0; b < 4; ++b) {
            const int r0 = (b == 0) ? 1 : 0;
            const int r1 = (b <= 1) ? 2 : 1;
            const int r2 = (b <= 2) ? 3 : 2;
            float m00 = sS[r0][c0], m01 = sS[r0][c1], m02 = sS[r0][c2];
            float m10 = sS[r1][c0], m11 = sS[r1][c1], m12 = sS[r1][c2];
            float m20 = sS[r2][c0], m21 = sS[r2][c1], m22 = sS[r2][c2];
            float d0 = fmaf(m11, m22, -m12*m21);
            float d1 = fmaf(m10, m22, -m12*m20);
            float d2 = fmaf(m10, m21, -m11*m20);
            float det3 = m00*d0 - m01*d1 + m02*d2;
            A.e[a][b] = (((a + b) & 1) ? -det3 : det3);
        }
    }
    return A;
}
// det via the verified pair-tree, using column j (bit-identical for all lanes):
// t_k = S[j][k]*adjE[k][j];  det = (t0+t1)+(t2+t3).
__device__ __forceinline__ float det4_colj(const Adj4& A, const float4& RJ, int j) {
    float a0j = sel4(A.e[0][0], A.e[0][1], A.e[0][2], A.e[0][3], j);
    float a1j = sel4(A.e[1][0], A.e[1][1], A.e[1][2], A.e[1][3], j);
    float a2j = sel4(A.e[2][0], A.e[2][1], A.e[2][2], A.e[2][3], j);
    float a3j = sel4(A.e[3][0], A.e[3][1], A.e[3][2], A.e[3][3], j);
    float t0 = RJ.x * a0j, t1 = RJ.y * a1j, t2 = RJ.z * a2j, t3 = RJ.w * a3j;
    return (t0 + t1) + (t2 + t3);
}

// Single-step potential: N(z'; F z, Qs) * prod_k N(y_k; b_k + z'_{h_k}, r)
__device__ __forceinline__ LP init_lane(float x0, float x1, const Cn& C, int i, int j) {
    LP P;
    float v = 0.0f;
    if (i == j) v = (i < 2) ? C.qa : C.qc;
    if ((i ^ j) == 2) v = C.wa;
    P.jFF = v;
    v = 0.0f;
    if (j == (i & 1))     v = (i < 2) ? -C.qa : -C.wa;
    if (j == (i & 1) + 2) v = (i < 2) ? -C.qb : -C.wb;
    P.jFL = v;
    P.jFB = 0.0f;
    v = 0.0f;
    if (i == j) v = ((i < 2) ? C.qa : C.qc) + (((i & 1) == 0) ? 2.0f*C.ri : 0.0f);
    if ((i ^ j) == 2) v = C.qb;
    P.jLL = v;
    P.jLB = (((i == 0) && (j < 2)) || ((i == 2) && (j >= 2))) ? C.ri : 0.0f;
    P.jBB = (i == j) ? C.ri : 0.0f;
    P.hF = 0.0f;
    P.hL = ((j & 1) == 0) ? C.ri * (x0 + x1) : 0.0f;
    P.hB = C.ri * ((j & 1) ? x1 : x0);
    P.g  = -C.ri * (x0*x0 + x1*x1) + C.Cstep;
    P.dm = 1.0f; P.de = 0.0f;
    return P;
}

// Compose P1 (earlier) o P2 (later), marginalizing the shared middle state.
// ONE staging round; everything else local.  Only same-wave LDS traffic.
__device__ __forceinline__ LP compose(const LP& P1, const LP& P2, float* gl, int i, int j) {
    float hm = P1.hL + P2.hF;      // lane holds hm[j]
    float Mb = P1.jLB + P2.jFB;    // M[i][j]
    float S  = P1.jLL + P2.jFF;    // S[i][j] (symmetric)
    float dm = P1.dm * P2.dm;
    float de = P1.de + P2.de;
    { int ex; dm = frexpf(dm, &ex); de += (float)ex; }
    const int ij = 4*i + j, ji = 4*j + i;

    // ---- single staging round ----
    gl[OFF_S   + ij] = S;
    gl[OFF_F1  + ij] = P1.jFL;      // F1 row-major
    gl[OFF_F2T + ji] = P2.jFL;      // F2 transposed (row a == F2[:,a])
    gl[OFF_MT  + ji] = Mb;          // M  transposed
    if (i == 0) gl[OFF_HM + j] = hm;
    LGKM0();
    float4 Ra = ld4(gl + OFF_S + 0);
    float4 Rb = ld4(gl + OFF_S + 4);
    float4 Rc = ld4(gl + OFF_S + 8);
    float4 Rd = ld4(gl + OFF_S + 12);
    float4 RJ = ld4(gl + OFF_S + 4*j);
    float4 f1r4 = ld4(gl + OFF_F1  + 4*i);   // F1[i,:]
    float4 f1T4 = ld4(gl + OFF_F1  + 4*j);   // F1[j,:]
    float4 f2c4 = ld4(gl + OFF_F2T + 4*j);   // F2[:,j]
    float4 f2T4 = ld4(gl + OFF_F2T + 4*i);   // F2[:,i]
    float4 mc4  = ld4(gl + OFF_MT  + 4*j);   // M[:,j]
    float4 mT4  = ld4(gl + OFF_MT  + 4*i);   // M[:,i]
    float4 hm4  = ld4(gl + OFF_HM);

    // ---- local full inverse ----
    Adj4 A = adj4(Ra, Rb, Rc, Rd);
    float det = det4_colj(A, RJ, j);
    dm *= det; { int ex; dm = frexpf(dm, &ex); de += (float)ex; }
    const float rdet = 1.0f / det;
    float4 sie0 = make_float4(A.e[0][0]*rdet, A.e[0][1]*rdet, A.e[0][2]*rdet, A.e[0][3]*rdet);
    float4 sie1 = make_float4(A.e[1][0]*rdet, A.e[1][1]*rdet, A.e[1][2]*rdet, A.e[1][3]*rdet);
    float4 sie2 = make_float4(A.e[2][0]*rdet, A.e[2][1]*rdet, A.e[2][2]*rdet, A.e[2][3]*rdet);
    float4 sie3 = make_float4(A.e[3][0]*rdet, A.e[3][1]*rdet, A.e[3][2]*rdet, A.e[3][3]*rdet);

    // ---- local intermediates (match staged values bit-for-bit) ----
    // A1[i,r] = dot(F1 row i, Si row r); A1[j,r] = dot(F1 row j, Si row r)
    float4 a1r4 = make_float4(dot4(f1r4, sie0), dot4(f1r4, sie1),
                              dot4(f1r4, sie2), dot4(f1r4, sie3));
    float4 a1j4 = make_float4(dot4(f1T4, sie0), dot4(f1T4, sie1),
                              dot4(f1T4, sie2), dot4(f1T4, sie3));
    // C1[r,j] = dot(Si row r, M[:,j]); B2[r,j] = dot(Si row r, F2[:,j])
    float4 c1c4 = make_float4(dot4(sie0, mc4), dot4(sie1, mc4),
                              dot4(sie2, mc4), dot4(sie3, mc4));
    float4 b2c4 = make_float4(dot4(sie0, f2c4), dot4(sie1, f2c4),
                              dot4(sie2, f2c4), dot4(sie3, f2c4));
    // v4[r] = dot(Si row r, hm)
    float4 v44  = make_float4(dot4(sie0, hm4), dot4(sie1, hm4),
                              dot4(sie2, hm4), dot4(sie3, hm4));

    LP R;
    R.jFF = P1.jFF - dot4(a1r4, f1T4);
    R.jFL = -dot4(a1r4, f2c4);
    R.jFB = P1.jFB - dot4(a1r4, mc4);
    R.jLL = P2.jLL - dot4(f2T4, b2c4);
    R.jLB = P2.jLB - dot4(f2T4, c1c4);
    R.jBB = P1.jBB + P2.jBB - dot4(mT4, c1c4);
    R.hF  = P1.hF - dot4(a1j4, hm4);
    R.hL  = P2.hL - dot4(f2c4, v44);
    R.hB  = P1.hB + P2.hB - dot4(mc4, v44);
    R.g   = P1.g + P2.g + 2.0f*(float)L2PI + 0.5f*dot4(hm4, v44);
    R.dm = dm; R.de = de;
    return R;
}

__device__ __forceinline__ LP fetchx(const LP& P, int m) {
    LP O;
    O.jFF = sx(P.jFF,m); O.jFL = sx(P.jFL,m); O.jFB = sx(P.jFB,m);
    O.jLL = sx(P.jLL,m); O.jLB = sx(P.jLB,m); O.jBB = sx(P.jBB,m);
    O.hF  = sx(P.hF,m);  O.hL  = sx(P.hL,m);  O.hB  = sx(P.hB,m);
    O.g   = sx(P.g,m);   O.dm  = sx(P.dm,m);  O.de  = sx(P.de,m);
    return O;
}
__device__ __forceinline__ LP csel(bool up, const LP& O, const LP& P) {
    LP A;
    A.jFF = up?O.jFF:P.jFF; A.jFL = up?O.jFL:P.jFL; A.jFB = up?O.jFB:P.jFB;
    A.jLL = up?O.jLL:P.jLL; A.jLB = up?O.jLB:P.jLB; A.jBB = up?O.jBB:P.jBB;
    A.hF  = up?O.hF :P.hF;  A.hL  = up?O.hL :P.hL;  A.hB  = up?O.hB :P.hB;
    A.g   = up?O.g  :P.g;   A.dm  = up?O.dm :P.dm;  A.de  = up?O.de :P.de;
    return A;
}
__device__ __forceinline__ void pot_store(float* p, const LP& P) {
    p[0]=P.jFF; p[1]=P.jFL; p[2]=P.jFB; p[3]=P.jLL; p[4]=P.jLB; p[5]=P.jBB;
    p[6]=P.hF;  p[7]=P.hL;  p[8]=P.hB;  p[9]=P.g;   p[10]=P.dm; p[11]=P.de;
}
__device__ __forceinline__ LP pot_load(const float* p) {
    LP P;
    P.jFF=p[0]; P.jFL=p[1]; P.jFB=p[2]; P.jLL=p[3]; P.jLB=p[4]; P.jBB=p[5];
    P.hF=p[6];  P.hL=p[7];  P.hB=p[8];  P.g=p[9];   P.dm=p[10]; P.de=p[11];
    return P;
}

// ---------- Kernel 1: produce.  32 blocks x 512 threads (8 waves).
// Each block folds 64 steps (32 groups x 2; depth 1+2+3=6) -> 1 pot in ws.
__global__ __launch_bounds__(512)
void hmm_produce(const float* __restrict__ track,
                 const float* __restrict__ obs_noise_p,
                 const float* __restrict__ trans_noise_p,
                 float* __restrict__ ws)
{
    __shared__ float pool[2][8][16][13];
    __shared__ __align__(16) float cbuf[32 * GSTRIDE];
    const int tid = (int)threadIdx.x;
    const int l = tid & 63, w = tid >> 6;
    const int i = (l >> 2) & 3, j = l & 3, g = (l >> 4) & 3;
    const int gid = w * 4 + g;            // group 0..31
    float* gl = &cbuf[(size_t)gid * GSTRIDE];
    const int bid = (int)blockIdx.x;

    const double sg2d = (double)obs_noise_p[0] * (double)obs_noise_p[0];
    const double qn2d = (double)trans_noise_p[0] * (double)trans_noise_p[0];

    Cn C;
    C.qa = (float)(12.0/qn2d); C.qb = (float)(-6.0/qn2d); C.qc = (float)(4.0/qn2d);
    C.wa = (float)(6.0/qn2d);  C.wb = (float)(-2.0/qn2d);
    C.ri = (float)(32.0/sg2d);
    C.Cstep = (float)(-2.0*log(2.0*M_PI*sg2d/32.0) - 2.0*L2PI
                      - 0.5*(4.0*log(qn2d) - 2.0*log(12.0)));

    const int t0 = (bid * 32 + gid) * 2;
    LP P;
    #pragma unroll 1
    for (int op = 0; op < 6; ++op) {
        LP A, Bp;
        if (op == 0) {
            A  = init_lane(track[2*t0+0], track[2*t0+1], C, i, j);
            Bp = init_lane(track[2*t0+2], track[2*t0+3], C, i, j);
        } else if (op < 3) {
            const int m = 16 << (op - 1);
            LP O = fetchx(P, m);
            const bool up = (l & m) != 0;
            A  = csel(up, O, P);
            Bp = csel(up, P, O);
        } else {
            const int s = 1 << (op - 3);
            const int buf = (op - 3) & 1;
            if (l < 16) pot_store(&pool[buf][w][l][0], P);
            __syncthreads();
            LP O = pot_load(&pool[buf][w ^ s][l & 15][0]);
            const bool up = (w & s) != 0;
            A  = csel(up, O, P);
            Bp = csel(up, P, O);
        }
        P = compose(A, Bp, gl, i, j);
    }
    if (w == 0 && l < 16)
        pot_store(ws + ((size_t)bid * 16 + l) * 12, P);
}

// ---------- Kernel 2: consume.  1 block x 512 threads.
// 32 groups load 1 pot each, depth 2+3=5 composes, finalize, expand. ----------
__global__ __launch_bounds__(512)
void hmm_consume(const float* __restrict__ bias_scales,
                 const float* __restrict__ obs_noise_p,
                 const float* __restrict__ ws,
                 float* __restrict__ out)
{
    __shared__ float pool[2][8][16][13];
    __shared__ __align__(16) float cbuf[32 * GSTRIDE];
    __shared__ float sTi[8][8];
    __shared__ float sA[4];
    __shared__ float sLL;
    const int tid = (int)threadIdx.x;
    const int l = tid & 63, w = tid >> 6;
    const int i = (l >> 2) & 3, j = l & 3, gb = l & 48, g = (l >> 4) & 3;
    const int gid = w * 4 + g;            // group 0..31
    float* gl = &cbuf[(size_t)gid * GSTRIDE];

    const double sg2d = (double)obs_noise_p[0] * (double)obs_noise_p[0];
    const double a00 = (double)bias_scales[0];
    const double a01 = (double)bias_scales[1];

    LP P = pot_load(ws + ((size_t)gid * 16 + (l & 15)) * 12);
    #pragma unroll 1
    for (int op = 0; op < 5; ++op) {
        LP A, Bp;
        if (op < 2) {
            const int m = 16 << op;
            LP O = fetchx(P, m);
            const bool up = (l & m) != 0;
            A  = csel(up, O, P);
            Bp = csel(up, P, O);
        } else {
            const int s = 1 << (op - 2);
            const int buf = (op - 2) & 1;
            if (l < 16) pot_store(&pool[buf][w][l][0], P);
            __syncthreads();
            LP O = pot_load(&pool[buf][w ^ s][l & 15][0]);
            const bool up = (w & s) != 0;
            A  = csel(up, O, P);
            Bp = csel(up, P, O);
        }
        P = compose(A, Bp, gl, i, j);
    }

    // ---------- final stage on wave 0 (local-inverse version) ----------
    if (w == 0) {
        const float a0i = (float)((i & 1) ? a01 : a00);
        P.jFF += (i == j) ? 1.0f : 0.0f;
        P.jBB += (i == j) ? 32.0f / a0i : 0.0f;
        P.g   += (float)(-4.0*L2PI + 2.0*log(32.0) - log(a00) - log(a01));
        float dm = P.dm, de = P.de;
        const int ij = 4*i + j, ji = 4*j + i;

        // single staging round: S rows, jFL^T, jFB^T, hF
        gl[OFF_S   + ij] = P.jFF;
        gl[OFF_F1  + ji] = P.jFL;   // transposed: row a == jFL[:,a]
        gl[OFF_F2T + ji] = P.jFB;   // transposed: row a == jFB[:,a]
        if (i == 0) gl[OFF_HM + j] = P.hF;
        LGKM0();
        float4 Ra = ld4(gl + OFF_S + 0);
        float4 Rb = ld4(gl + OFF_S + 4);
        float4 Rc = ld4(gl + OFF_S + 8);
        float4 Rd = ld4(gl + OFF_S + 12);
        float4 RJ = ld4(gl + OFF_S + 4*j);
        float4 fr4 = ld4(gl + OFF_F1  + 4*i);   // jFL[:,i]
        float4 fT4 = ld4(gl + OFF_F1  + 4*j);   // jFL[:,j]
        float4 bc4 = ld4(gl + OFF_F2T + 4*i);   // jFB[:,i]
        float4 bT4 = ld4(gl + OFF_F2T + 4*j);   // jFB[:,j]
        float4 hf4 = ld4(gl + OFF_HM);

        Adj4 A = adj4(Ra, Rb, Rc, Rd);
        float det = det4_colj(A, RJ, j);
        dm *= det; { int ex; dm = frexpf(dm, &ex); de += (float)ex; }
        const float rdet = 1.0f / det;
        float4 sie0 = make_float4(A.e[0][0]*rdet, A.e[0][1]*rdet, A.e[0][2]*rdet, A.e[0][3]*rdet);
        float4 sie1 = make_float4(A.e[1][0]*rdet, A.e[1][1]*rdet, A.e[1][2]*rdet, A.e[1][3]*rdet);
        float4 sie2 = make_float4(A.e[2][0]*rdet, A.e[2][1]*rdet, A.e[2][2]*rdet, A.e[2][3]*rdet);
        float4 sie3 = make_float4(A.e[3][0]*rdet, A.e[3][1]*rdet, A.e[3][2]*rdet, A.e[3][3]*rdet);

        // ylc[r] = dot(Si row r, jFL[:,j]); ybc[r] = dot(Si row r, jFB[:,j]);
        // yfc[r] = dot(Si row r, hF)
        float4 ylc4 = make_float4(dot4(sie0, fT4), dot4(sie1, fT4),
                                  dot4(sie2, fT4), dot4(sie3, fT4));
        float4 ybc4 = make_float4(dot4(sie0, bT4), dot4(sie1, bT4),
                                  dot4(sie2, bT4), dot4(sie3, bT4));
        float4 yfc4 = make_float4(dot4(sie0, hf4), dot4(sie1, hf4),
                                  dot4(sie2, hf4), dot4(sie3, hf4));
        float s1  = dot4(fr4, ylc4);
        float s2  = dot4(fr4, ybc4);
        float s3  = dot4(bc4, ybc4);
        float sh1 = dot4(fT4, yfc4);
        float sh2 = dot4(bT4, yfc4);
        float qF  = dot4(hf4, yfc4);

        float J8ss = P.jLL - s1;
        float J8sb = P.jLB - s2;
        float J8bb = P.jBB - s3;
        float h8s  = P.hL - sh1;
        float h8b  = P.hB - sh2;
        float g8   = P.g + 2.0f*(float)L2PI + 0.5f*qF;

        // 8x8 stage across all 64 lanes: lane = (I,J)
        const int I = l >> 3, J = l & 7, i4 = I & 3, j4 = J & 3;
        float ss  = shf(J8ss, 4*i4 + j4);
        float sb  = shf(J8sb, 4*i4 + j4);
        float sbT = shf(J8sb, 4*j4 + i4);
        float bb  = shf(J8bb, 4*i4 + j4);
        float A8 = (I < 4) ? ((J < 4) ? ss : sb) : ((J < 4) ? sbT : bb);
        const float J8sav = A8;
        float h8v = (J < 4) ? shf(h8s, j4) : shf(h8b, j4);
        float h8r = (I < 4) ? shf(h8s, i4) : shf(h8b, i4);
        float K8 = (I == J) ? 1.0f : 0.0f;
        #pragma unroll 1
        for (int p = 0; p < 8; ++p) {
            float piv = shf(A8, 9*p);
            dm *= piv; { int ex; dm = frexpf(dm, &ex); de += (float)ex; }
            float ip = 1.0f / piv;
            float Ap = shf(A8, 8*p + J) * ip;
            float Kp = shf(K8, 8*p + J) * ip;
            float f  = shf(A8, 8*I + p);
            bool isp = (I == p);
            A8 = isp ? A8 * ip : fmaf(-f, Ap, A8);
            K8 = isp ? K8 * ip : fmaf(-f, Kp, K8);
        }
        float tq = h8r * K8 * h8v;
        tq += sx(tq,1); tq += sx(tq,2); tq += sx(tq,4);
        tq += sx(tq,8); tq += sx(tq,16); tq += sx(tq,32);

        double ll = (double)g8 + 4.0*L2PI
                    - 0.5*(log((double)dm) + (double)de*LN2) + 0.5*(double)tq;
        const double Td = 2048.0;
        const double c0d = sg2d/a00, c1d = sg2d/a01;
        ll += -31.0*(Td*(L2PI + log(sg2d)) + log((c0d+Td)/c0d))
              -31.0*(Td*(L2PI + log(sg2d)) + log((c1d+Td)/c1d))
              -2.0*Td*log(32.0);

        const float i32 = 1.0f/32.0f, irn = 0.176776695296637f;
        int a = (I >= 4) ? I - 4 : I + 4;
        int b = (J >= 4) ? J - 4 : J + 4;
        float scale = (I >= 4 && J >= 4) ? i32 : (((I >= 4) != (J >= 4)) ? irn : 1.0f);
        sTi[a][b] = J8sav * scale;
        if (l < 4) {
            double a0k = (l & 1) ? a01 : a00;
            sA[l] = (float)(a0k*sg2d/(sg2d + Td*a0k));
        }
        if (l == 0) sLL = (float)ll;
    }
    __syncthreads();

    // ---------- expand 1 + 132x132 outputs ----------
    const float inv32 = 1.0f/32.0f;
    const float invrn = 0.176776695296637f;
    const int total = 1 + 132*132;
    #pragma unroll 1
    for (int idx = tid; idx < total; idx += 512) {
        float v;
        if (idx == 0) {
            v = sLL;
        } else {
            int el = idx - 1;
            int r = el / 132;
            int cc = el - 132*r;
            if (r < 128) {
                int ki = ((r >> 6) << 1) | (r & 1);
                if (cc < 128) {
                    int kj = ((cc >> 6) << 1) | (cc & 1);
                    v = sTi[ki][kj] * inv32;
                    if (ki == kj) {
                        float ia = 1.0f / sA[ki];
                        v -= ia * inv32;
                        if (r == cc) v += ia;
                    }
                } else {
                    v = sTi[ki][cc - 124] * invrn;
                }
            } else {
                if (cc < 128) {
                    int kj = ((cc >> 6) << 1) | (cc & 1);
                    v = sTi[kj][r - 124] * invrn;
                } else {
                    v = sTi[r - 124][cc - 124];
                }
            }
        }
        out[idx] = v;
    }
}

extern "C" void kernel_launch(void* const* d_in, const int* in_sizes, int n_in,
                              void* d_out, int out_size, void* d_ws, size_t ws_size,
                              hipStream_t stream) {
    (void)in_sizes; (void)n_in; (void)out_size; (void)ws_size;
    const float* track       = (const float*)d_in[0];
    const float* bias_scales = (const float*)d_in[1];
    const float* obs_noise   = (const float*)d_in[2];
    const float* trans_noise = (const float*)d_in[3];
    float* out = (float*)d_out;
    float* ws  = (float*)d_ws;   // 24 KB pots; coherence via kernel boundary
    hipLaunchKernelGGL(hmm_produce, dim3(32), dim3(512), 0, stream,
                       track, obs_noise, trans_noise, ws);
    hipLaunchKernelGGL(hmm_consume, dim3(1), dim3(512), 0, stream,
                       bias_scales, obs_noise, ws, out);
}

// Round 7
// 82.391 us; speedup vs baseline: 1.1267x; 1.0781x over previous
//
#include <hip/hip_runtime.h>
#include <math.h>

#define L2PI 1.8378770664093454835606594728112
#define LN2  0.69314718055994530941723212145818

// ---------------------------------------------------------------------------
// Lane-parallel Gaussian potential (fp32) over (F = first state(4),
// L = last state(4), B = class-bias means(4)).  16 lanes per potential;
// lane (i,j) holds element (i,j) of each 4x4 J block; h vectors replicated
// over rows (lane (i,j) holds h[j]); g/dm/de replicated.
//
// Round 7: 3 dispatches.  produce (32 blk) -> tree (1 blk, composes+final,
// writes 69-float blob) -> expand (69 blk, writeout).  Vectorized pot I/O,
// hoisted f64 consts.  All math identical to verified round-6 kernels.
// ---------------------------------------------------------------------------
struct LP {
    float jFF, jFL, jFB, jLL, jLB, jBB;
    float hF, hL, hB, g, dm, de;
};

struct Cn { float qa, qb, qc, wa, wb, ri, Cstep; };

__device__ __forceinline__ float shf(float v, int s) { return __shfl(v, s, 64); }
__device__ __forceinline__ float sx (float v, int m) { return __shfl_xor(v, m, 64); }

#define LGKM0() do { \
    asm volatile("s_waitcnt lgkmcnt(0)" ::: "memory"); \
    __builtin_amdgcn_sched_barrier(0); \
} while (0)

#define OFF_S   0
#define OFF_F1  16
#define OFF_F2T 32
#define OFF_MT  48
#define OFF_HM  64
#define GSTRIDE 152

// result blob at float offset 8192 (=+32 KB, proven in-bounds since round 0):
// [0]=sLL, [1..64]=sTi[8][8], [65..68]=sA[4]
#define WSR_OFF 8192

__device__ __forceinline__ float4 ld4(const float* p) {
    return *(const float4*)p;
}
__device__ __forceinline__ float dot4(float4 a, float4 b) {
    float s = a.x * b.x;
    s = fmaf(a.y, b.y, s);
    s = fmaf(a.z, b.z, s);
    s = fmaf(a.w, b.w, s);
    return s;
}
__device__ __forceinline__ float sel4(float x0, float x1, float x2, float x3, int k) {
    return (k == 0) ? x0 : ((k == 1) ? x1 : ((k == 2) ? x2 : x3));
}

struct Adj4 { float e[4][4]; };
__device__ __forceinline__ Adj4 adj4(const float4& Ra, const float4& Rb,
                                     const float4& Rc, const float4& Rd) {
    float sS[4][4];
    sS[0][0]=Ra.x; sS[0][1]=Ra.y; sS[0][2]=Ra.z; sS[0][3]=Ra.w;
    sS[1][0]=Rb.x; sS[1][1]=Rb.y; sS[1][2]=Rb.z; sS[1][3]=Rb.w;
    sS[2][0]=Rc.x; sS[2][1]=Rc.y; sS[2][2]=Rc.z; sS[2][3]=Rc.w;
    sS[3][0]=Rd.x; sS[3][1]=Rd.y; sS[3][2]=Rd.z; sS[3][3]=Rd.w;
    Adj4 A;
    #pragma unroll
    for (int a = 0; a < 4; ++a) {
        const int c0 = (a == 0) ? 1 : 0;
        const int c1 = (a <= 1) ? 2 : 1;
        const int c2 = (a <= 2) ? 3 : 2;
        #pragma unroll
        for (int b = 0; b < 4; ++b) {
            const int r0 = (b == 0) ? 1 : 0;
            const int r1 = (b <= 1) ? 2 : 1;
            const int r2 = (b <= 2) ? 3 : 2;
            float m00 = sS[r0][c0], m01 = sS[r0][c1], m02 = sS[r0][c2];
            float m10 = sS[r1][c0], m11 = sS[r1][c1], m12 = sS[r1][c2];
            float m20 = sS[r2][c0], m21 = sS[r2][c1], m22 = sS[r2][c2];
            float d0 = fmaf(m11, m22, -m12*m21);
            float d1 = fmaf(m10, m22, -m12*m20);
            float d2 = fmaf(m10, m21, -m11*m20);
            float det3 = m00*d0 - m01*d1 + m02*d2;
            A.e[a][b] = (((a + b) & 1) ? -det3 : det3);
        }
    }
    return A;
}
__device__ __forceinline__ float det4_colj(const Adj4& A, const float4& RJ, int j) {
    float a0j = sel4(A.e[0][0], A.e[0][1], A.e[0][2], A.e[0][3], j);
    float a1j = sel4(A.e[1][0], A.e[1][1], A.e[1][2], A.e[1][3], j);
    float a2j = sel4(A.e[2][0], A.e[2][1], A.e[2][2], A.e[2][3], j);
    float a3j = sel4(A.e[3][0], A.e[3][1], A.e[3][2], A.e[3][3], j);
    float t0 = RJ.x * a0j, t1 = RJ.y * a1j, t2 = RJ.z * a2j, t3 = RJ.w * a3j;
    return (t0 + t1) + (t2 + t3);
}

__device__ __forceinline__ LP init_lane(float x0, float x1, const Cn& C, int i, int j) {
    LP P;
    float v = 0.0f;
    if (i == j) v = (i < 2) ? C.qa : C.qc;
    if ((i ^ j) == 2) v = C.wa;
    P.jFF = v;
    v = 0.0f;
    if (j == (i & 1))     v = (i < 2) ? -C.qa : -C.wa;
    if (j == (i & 1) + 2) v = (i < 2) ? -C.qb : -C.wb;
    P.jFL = v;
    P.jFB = 0.0f;
    v = 0.0f;
    if (i == j) v = ((i < 2) ? C.qa : C.qc) + (((i & 1) == 0) ? 2.0f*C.ri : 0.0f);
    if ((i ^ j) == 2) v = C.qb;
    P.jLL = v;
    P.jLB = (((i == 0) && (j < 2)) || ((i == 2) && (j >= 2))) ? C.ri : 0.0f;
    P.jBB = (i == j) ? C.ri : 0.0f;
    P.hF = 0.0f;
    P.hL = ((j & 1) == 0) ? C.ri * (x0 + x1) : 0.0f;
    P.hB = C.ri * ((j & 1) ? x1 : x0);
    P.g  = -C.ri * (x0*x0 + x1*x1) + C.Cstep;
    P.dm = 1.0f; P.de = 0.0f;
    return P;
}

// Compose P1 (earlier) o P2 (later): one LDS staging round, local inverse.
__device__ __forceinline__ LP compose(const LP& P1, const LP& P2, float* gl, int i, int j) {
    float hm = P1.hL + P2.hF;
    float Mb = P1.jLB + P2.jFB;
    float S  = P1.jLL + P2.jFF;
    float dm = P1.dm * P2.dm;
    float de = P1.de + P2.de;
    { int ex; dm = frexpf(dm, &ex); de += (float)ex; }
    const int ij = 4*i + j, ji = 4*j + i;

    gl[OFF_S   + ij] = S;
    gl[OFF_F1  + ij] = P1.jFL;
    gl[OFF_F2T + ji] = P2.jFL;
    gl[OFF_MT  + ji] = Mb;
    if (i == 0) gl[OFF_HM + j] = hm;
    LGKM0();
    float4 Ra = ld4(gl + OFF_S + 0);
    float4 Rb = ld4(gl + OFF_S + 4);
    float4 Rc = ld4(gl + OFF_S + 8);
    float4 Rd = ld4(gl + OFF_S + 12);
    float4 RJ = ld4(gl + OFF_S + 4*j);
    float4 f1r4 = ld4(gl + OFF_F1  + 4*i);
    float4 f1T4 = ld4(gl + OFF_F1  + 4*j);
    float4 f2c4 = ld4(gl + OFF_F2T + 4*j);
    float4 f2T4 = ld4(gl + OFF_F2T + 4*i);
    float4 mc4  = ld4(gl + OFF_MT  + 4*j);
    float4 mT4  = ld4(gl + OFF_MT  + 4*i);
    float4 hm4  = ld4(gl + OFF_HM);

    Adj4 A = adj4(Ra, Rb, Rc, Rd);
    float det = det4_colj(A, RJ, j);
    dm *= det; { int ex; dm = frexpf(dm, &ex); de += (float)ex; }
    const float rdet = 1.0f / det;
    float4 sie0 = make_float4(A.e[0][0]*rdet, A.e[0][1]*rdet, A.e[0][2]*rdet, A.e[0][3]*rdet);
    float4 sie1 = make_float4(A.e[1][0]*rdet, A.e[1][1]*rdet, A.e[1][2]*rdet, A.e[1][3]*rdet);
    float4 sie2 = make_float4(A.e[2][0]*rdet, A.e[2][1]*rdet, A.e[2][2]*rdet, A.e[2][3]*rdet);
    float4 sie3 = make_float4(A.e[3][0]*rdet, A.e[3][1]*rdet, A.e[3][2]*rdet, A.e[3][3]*rdet);

    float4 a1r4 = make_float4(dot4(f1r4, sie0), dot4(f1r4, sie1),
                              dot4(f1r4, sie2), dot4(f1r4, sie3));
    float4 a1j4 = make_float4(dot4(f1T4, sie0), dot4(f1T4, sie1),
                              dot4(f1T4, sie2), dot4(f1T4, sie3));
    float4 c1c4 = make_float4(dot4(sie0, mc4), dot4(sie1, mc4),
                              dot4(sie2, mc4), dot4(sie3, mc4));
    float4 b2c4 = make_float4(dot4(sie0, f2c4), dot4(sie1, f2c4),
                              dot4(sie2, f2c4), dot4(sie3, f2c4));
    float4 v44  = make_float4(dot4(sie0, hm4), dot4(sie1, hm4),
                              dot4(sie2, hm4), dot4(sie3, hm4));

    LP R;
    R.jFF = P1.jFF - dot4(a1r4, f1T4);
    R.jFL = -dot4(a1r4, f2c4);
    R.jFB = P1.jFB - dot4(a1r4, mc4);
    R.jLL = P2.jLL - dot4(f2T4, b2c4);
    R.jLB = P2.jLB - dot4(f2T4, c1c4);
    R.jBB = P1.jBB + P2.jBB - dot4(mT4, c1c4);
    R.hF  = P1.hF - dot4(a1j4, hm4);
    R.hL  = P2.hL - dot4(f2c4, v44);
    R.hB  = P1.hB + P2.hB - dot4(mc4, v44);
    R.g   = P1.g + P2.g + 2.0f*(float)L2PI + 0.5f*dot4(hm4, v44);
    R.dm = dm; R.de = de;
    return R;
}

__device__ __forceinline__ LP fetchx(const LP& P, int m) {
    LP O;
    O.jFF = sx(P.jFF,m); O.jFL = sx(P.jFL,m); O.jFB = sx(P.jFB,m);
    O.jLL = sx(P.jLL,m); O.jLB = sx(P.jLB,m); O.jBB = sx(P.jBB,m);
    O.hF  = sx(P.hF,m);  O.hL  = sx(P.hL,m);  O.hB  = sx(P.hB,m);
    O.g   = sx(P.g,m);   O.dm  = sx(P.dm,m);  O.de  = sx(P.de,m);
    return O;
}
__device__ __forceinline__ LP csel(bool up, const LP& O, const LP& P) {
    LP A;
    A.jFF = up?O.jFF:P.jFF; A.jFL = up?O.jFL:P.jFL; A.jFB = up?O.jFB:P.jFB;
    A.jLL = up?O.jLL:P.jLL; A.jLB = up?O.jLB:P.jLB; A.jBB = up?O.jBB:P.jBB;
    A.hF  = up?O.hF :P.hF;  A.hL  = up?O.hL :P.hL;  A.hB  = up?O.hB :P.hB;
    A.g   = up?O.g  :P.g;   A.dm  = up?O.dm :P.dm;  A.de  = up?O.de :P.de;
    return A;
}
// LDS pool (stride 13, 4B-aligned) stays scalar:
__device__ __forceinline__ void pot_store(float* p, const LP& P) {
    p[0]=P.jFF; p[1]=P.jFL; p[2]=P.jFB; p[3]=P.jLL; p[4]=P.jLB; p[5]=P.jBB;
    p[6]=P.hF;  p[7]=P.hL;  p[8]=P.hB;  p[9]=P.g;   p[10]=P.dm; p[11]=P.de;
}
__device__ __forceinline__ LP pot_load(const float* p) {
    LP P;
    P.jFF=p[0]; P.jFL=p[1]; P.jFB=p[2]; P.jLL=p[3]; P.jLB=p[4]; P.jBB=p[5];
    P.hF=p[6];  P.hL=p[7];  P.hB=p[8];  P.g=p[9];   P.dm=p[10]; P.de=p[11];
    return P;
}
// global pot I/O (48B stride -> 16B aligned): vectorized float4 x3
__device__ __forceinline__ void pot_store4(float* p, const LP& P) {
    *(float4*)(p + 0) = make_float4(P.jFF, P.jFL, P.jFB, P.jLL);
    *(float4*)(p + 4) = make_float4(P.jLB, P.jBB, P.hF,  P.hL);
    *(float4*)(p + 8) = make_float4(P.hB,  P.g,   P.dm,  P.de);
}
__device__ __forceinline__ LP pot_load4(const float* p) {
    float4 a = ld4(p + 0), b = ld4(p + 4), c = ld4(p + 8);
    LP P;
    P.jFF=a.x; P.jFL=a.y; P.jFB=a.z; P.jLL=a.w;
    P.jLB=b.x; P.jBB=b.y; P.hF=b.z;  P.hL=b.w;
    P.hB=c.x;  P.g=c.y;   P.dm=c.z;  P.de=c.w;
    return P;
}

// ---------- Kernel 1: produce.  32 blocks x 512 threads. ----------
__global__ __launch_bounds__(512)
void hmm_produce(const float* __restrict__ track,
                 const float* __restrict__ obs_noise_p,
                 const float* __restrict__ trans_noise_p,
                 float* __restrict__ ws)
{
    __shared__ float pool[2][8][16][13];
    __shared__ __align__(16) float cbuf[32 * GSTRIDE];
    const int tid = (int)threadIdx.x;
    const int l = tid & 63, w = tid >> 6;
    const int i = (l >> 2) & 3, j = l & 3, g = (l >> 4) & 3;
    const int gid = w * 4 + g;
    float* gl = &cbuf[(size_t)gid * GSTRIDE];
    const int bid = (int)blockIdx.x;

    const double sg2d = (double)obs_noise_p[0] * (double)obs_noise_p[0];
    const double qn2d = (double)trans_noise_p[0] * (double)trans_noise_p[0];

    Cn C;
    C.qa = (float)(12.0/qn2d); C.qb = (float)(-6.0/qn2d); C.qc = (float)(4.0/qn2d);
    C.wa = (float)(6.0/qn2d);  C.wb = (float)(-2.0/qn2d);
    C.ri = (float)(32.0/sg2d);
    C.Cstep = (float)(-2.0*log(2.0*M_PI*sg2d/32.0) - 2.0*L2PI
                      - 0.5*(4.0*log(qn2d) - 2.0*log(12.0)));

    const int t0 = (bid * 32 + gid) * 2;
    LP P;
    #pragma unroll 1
    for (int op = 0; op < 6; ++op) {
        LP A, Bp;
        if (op == 0) {
            A  = init_lane(track[2*t0+0], track[2*t0+1], C, i, j);
            Bp = init_lane(track[2*t0+2], track[2*t0+3], C, i, j);
        } else if (op < 3) {
            const int m = 16 << (op - 1);
            LP O = fetchx(P, m);
            const bool up = (l & m) != 0;
            A  = csel(up, O, P);
            Bp = csel(up, P, O);
        } else {
            const int s = 1 << (op - 3);
            const int buf = (op - 3) & 1;
            if (l < 16) pot_store(&pool[buf][w][l][0], P);
            __syncthreads();
            LP O = pot_load(&pool[buf][w ^ s][l & 15][0]);
            const bool up = (w & s) != 0;
            A  = csel(up, O, P);
            Bp = csel(up, P, O);
        }
        P = compose(A, Bp, gl, i, j);
    }
    if (w == 0 && l < 16)
        pot_store4(ws + ((size_t)bid * 16 + l) * 12, P);
}

// ---------- Kernel 2: tree.  1 block x 512 threads.
// 5 composes + final + GJ; writes 69-float blob to ws+WSR_OFF. ----------
__global__ __launch_bounds__(512)
void hmm_tree(const float* __restrict__ bias_scales,
              const float* __restrict__ obs_noise_p,
              float* __restrict__ ws)
{
    __shared__ float pool[2][8][16][13];
    __shared__ __align__(16) float cbuf[32 * GSTRIDE];
    const int tid = (int)threadIdx.x;
    const int l = tid & 63, w = tid >> 6;
    const int i = (l >> 2) & 3, j = l & 3, g = (l >> 4) & 3;
    const int gid = w * 4 + g;
    float* gl = &cbuf[(size_t)gid * GSTRIDE];
    float* wsr = ws + WSR_OFF;

    // ---- hoisted input-only constants (identical expressions -> identical
    // values); issued early so the f64 logs overlap the cold pot loads ----
    const double sg2d = (double)obs_noise_p[0] * (double)obs_noise_p[0];
    const double a00 = (double)bias_scales[0];
    const double a01 = (double)bias_scales[1];
    const double Td = 2048.0;
    const double c0d = sg2d/a00, c1d = sg2d/a01;
    const double llconst = -31.0*(Td*(L2PI + log(sg2d)) + log((c0d+Td)/c0d))
                           -31.0*(Td*(L2PI + log(sg2d)) + log((c1d+Td)/c1d))
                           -2.0*Td*log(32.0);
    const float gconst = (float)(-4.0*L2PI + 2.0*log(32.0) - log(a00) - log(a01));

    LP P = pot_load4(ws + ((size_t)gid * 16 + (l & 15)) * 12);
    #pragma unroll 1
    for (int op = 0; op < 5; ++op) {
        LP A, Bp;
        if (op < 2) {
            const int m = 16 << op;
            LP O = fetchx(P, m);
            const bool up = (l & m) != 0;
            A  = csel(up, O, P);
            Bp = csel(up, P, O);
        } else {
            const int s = 1 << (op - 2);
            const int buf = (op - 2) & 1;
            if (l < 16) pot_store(&pool[buf][w][l][0], P);
            __syncthreads();
            LP O = pot_load(&pool[buf][w ^ s][l & 15][0]);
            const bool up = (w & s) != 0;
            A  = csel(up, O, P);
            Bp = csel(up, P, O);
        }
        P = compose(A, Bp, gl, i, j);
    }

    // ---------- final stage on wave 0 ----------
    if (w == 0) {
        const float a0i = (float)((i & 1) ? a01 : a00);
        P.jFF += (i == j) ? 1.0f : 0.0f;
        P.jBB += (i == j) ? 32.0f / a0i : 0.0f;
        P.g   += gconst;
        float dm = P.dm, de = P.de;
        const int ij = 4*i + j, ji = 4*j + i;

        gl[OFF_S   + ij] = P.jFF;
        gl[OFF_F1  + ji] = P.jFL;   // transposed
        gl[OFF_F2T + ji] = P.jFB;   // transposed
        if (i == 0) gl[OFF_HM + j] = P.hF;
        LGKM0();
        float4 Ra = ld4(gl + OFF_S + 0);
        float4 Rb = ld4(gl + OFF_S + 4);
        float4 Rc = ld4(gl + OFF_S + 8);
        float4 Rd = ld4(gl + OFF_S + 12);
        float4 RJ = ld4(gl + OFF_S + 4*j);
        float4 fr4 = ld4(gl + OFF_F1  + 4*i);
        float4 fT4 = ld4(gl + OFF_F1  + 4*j);
        float4 bc4 = ld4(gl + OFF_F2T + 4*i);
        float4 bT4 = ld4(gl + OFF_F2T + 4*j);
        float4 hf4 = ld4(gl + OFF_HM);

        Adj4 A = adj4(Ra, Rb, Rc, Rd);
        float det = det4_colj(A, RJ, j);
        dm *= det; { int ex; dm = frexpf(dm, &ex); de += (float)ex; }
        const float rdet = 1.0f / det;
        float4 sie0 = make_float4(A.e[0][0]*rdet, A.e[0][1]*rdet, A.e[0][2]*rdet, A.e[0][3]*rdet);
        float4 sie1 = make_float4(A.e[1][0]*rdet, A.e[1][1]*rdet, A.e[1][2]*rdet, A.e[1][3]*rdet);
        float4 sie2 = make_float4(A.e[2][0]*rdet, A.e[2][1]*rdet, A.e[2][2]*rdet, A.e[2][3]*rdet);
        float4 sie3 = make_float4(A.e[3][0]*rdet, A.e[3][1]*rdet, A.e[3][2]*rdet, A.e[3][3]*rdet);

        float4 ylc4 = make_float4(dot4(sie0, fT4), dot4(sie1, fT4),
                                  dot4(sie2, fT4), dot4(sie3, fT4));
        float4 ybc4 = make_float4(dot4(sie0, bT4), dot4(sie1, bT4),
                                  dot4(sie2, bT4), dot4(sie3, bT4));
        float4 yfc4 = make_float4(dot4(sie0, hf4), dot4(sie1, hf4),
                                  dot4(sie2, hf4), dot4(sie3, hf4));
        float s1  = dot4(fr4, ylc4);
        float s2  = dot4(fr4, ybc4);
        float s3  = dot4(bc4, ybc4);
        float sh1 = dot4(fT4, yfc4);
        float sh2 = dot4(bT4, yfc4);
        float qF  = dot4(hf4, yfc4);

        float J8ss = P.jLL - s1;
        float J8sb = P.jLB - s2;
        float J8bb = P.jBB - s3;
        float h8s  = P.hL - sh1;
        float h8b  = P.hB - sh2;
        float g8   = P.g + 2.0f*(float)L2PI + 0.5f*qF;

        // 8x8 stage across all 64 lanes: lane = (I,J)
        const int I = l >> 3, J = l & 7, i4 = I & 3, j4 = J & 3;
        float ss  = shf(J8ss, 4*i4 + j4);
        float sb  = shf(J8sb, 4*i4 + j4);
        float sbT = shf(J8sb, 4*j4 + i4);
        float bb  = shf(J8bb, 4*i4 + j4);
        float A8 = (I < 4) ? ((J < 4) ? ss : sb) : ((J < 4) ? sbT : bb);
        const float J8sav = A8;
        float h8v = (J < 4) ? shf(h8s, j4) : shf(h8b, j4);
        float h8r = (I < 4) ? shf(h8s, i4) : shf(h8b, i4);
        float K8 = (I == J) ? 1.0f : 0.0f;
        #pragma unroll 1
        for (int p = 0; p < 8; ++p) {
            float piv = shf(A8, 9*p);
            dm *= piv; { int ex; dm = frexpf(dm, &ex); de += (float)ex; }
            float ip = 1.0f / piv;
            float Ap = shf(A8, 8*p + J) * ip;
            float Kp = shf(K8, 8*p + J) * ip;
            float f  = shf(A8, 8*I + p);
            bool isp = (I == p);
            A8 = isp ? A8 * ip : fmaf(-f, Ap, A8);
            K8 = isp ? K8 * ip : fmaf(-f, Kp, K8);
        }
        float tq = h8r * K8 * h8v;
        tq += sx(tq,1); tq += sx(tq,2); tq += sx(tq,4);
        tq += sx(tq,8); tq += sx(tq,16); tq += sx(tq,32);

        double ll = (double)g8 + 4.0*L2PI
                    - 0.5*(log((double)dm) + (double)de*LN2) + 0.5*(double)tq;
        ll += llconst;

        const float i32 = 1.0f/32.0f, irn = 0.176776695296637f;
        int a = (I >= 4) ? I - 4 : I + 4;
        int b = (J >= 4) ? J - 4 : J + 4;
        float scale = (I >= 4 && J >= 4) ? i32 : (((I >= 4) != (J >= 4)) ? irn : 1.0f);
        wsr[1 + 8*a + b] = J8sav * scale;
        if (l < 4) {
            double a0k = (l & 1) ? a01 : a00;
            wsr[65 + l] = (float)(a0k*sg2d/(sg2d + Td*a0k));
        }
        if (l == 0) wsr[0] = (float)ll;
    }
}

// ---------- Kernel 3: expand.  69 blocks x 256 threads, fully parallel. ----
__global__ __launch_bounds__(256)
void hmm_expand(const float* __restrict__ wsr,
                float* __restrict__ out)
{
    const int idx = (int)blockIdx.x * 256 + (int)threadIdx.x;
    const int total = 1 + 132*132;
    if (idx >= total) return;
    const float inv32 = 1.0f/32.0f;
    const float invrn = 0.176776695296637f;
    float v;
    if (idx == 0) {
        v = wsr[0];
    } else {
        int el = idx - 1;
        int r = el / 132;
        int cc = el - 132*r;
        if (r < 128) {
            int ki = ((r >> 6) << 1) | (r & 1);
            if (cc < 128) {
                int kj = ((cc >> 6) << 1) | (cc & 1);
                v = wsr[1 + 8*ki + kj] * inv32;
                if (ki == kj) {
                    float ia = 1.0f / wsr[65 + ki];
                    v -= ia * inv32;
                    if (r == cc) v += ia;
                }
            } else {
                v = wsr[1 + 8*ki + (cc - 124)] * invrn;
            }
        } else {
            if (cc < 128) {
                int kj = ((cc >> 6) << 1) | (cc & 1);
                v = wsr[1 + 8*kj + (r - 124)] * invrn;
            } else {
                v = wsr[1 + 8*(r - 124) + (cc - 124)];
            }
        }
    }
    out[idx] = v;
}

extern "C" void kernel_launch(void* const* d_in, const int* in_sizes, int n_in,
                              void* d_out, int out_size, void* d_ws, size_t ws_size,
                              hipStream_t stream) {
    (void)in_sizes; (void)n_in; (void)out_size; (void)ws_size;
    const float* track       = (const float*)d_in[0];
    const float* bias_scales = (const float*)d_in[1];
    const float* obs_noise   = (const float*)d_in[2];
    const float* trans_noise = (const float*)d_in[3];
    float* out = (float*)d_out;
    float* ws  = (float*)d_ws;   // pots 24 KB; result blob at +32 KB
    hipLaunchKernelGGL(hmm_produce, dim3(32), dim3(512), 0, stream,
                       track, obs_noise, trans_noise, ws);
    hipLaunchKernelGGL(hmm_tree, dim3(1), dim3(512), 0, stream,
                       bias_scales, obs_noise, ws);
    hipLaunchKernelGGL(hmm_expand, dim3(69), dim3(256), 0, stream,
                       (const float*)(ws + WSR_OFF), out);
}

// Round 9
// 81.357 us; speedup vs baseline: 1.1411x; 1.0127x over previous
//
#include <hip/hip_runtime.h>
#include <math.h>

#define L2PI 1.8378770664093454835606594728112
#define LN2  0.69314718055994530941723212145818

// ---------------------------------------------------------------------------
// Lane-parallel Gaussian potential (fp32) over (F = first state(4),
// L = last state(4), B = class-bias means(4)).  16 lanes per potential.
//
// Round 9 (= round 8 resubmitted after infra flake): regime-specialized
// compose.
//  - produce (32 blk, parallel): local-inverse compose (R6/R7 verified) —
//    1 LDS round-trip, redundant VALU is free across blocks.
//  - tree (1 blk, serial latency-bound): R4's 3-round staged compose +
//    R4's shuffle-based final stage — smaller code, shorter dependent chain
//    (R4 evidence: that consume ran <39.1 µs vs R6's 44.3).
// All math bit-identical to harness-verified rounds 4 and 7.
// ---------------------------------------------------------------------------
struct LP {
    float jFF, jFL, jFB, jLL, jLB, jBB;
    float hF, hL, hB, g, dm, de;
};

struct Cn { float qa, qb, qc, wa, wb, ri, Cstep; };

__device__ __forceinline__ float shf(float v, int s) { return __shfl(v, s, 64); }
__device__ __forceinline__ float sx (float v, int m) { return __shfl_xor(v, m, 64); }

#define LGKM0() do { \
    asm volatile("s_waitcnt lgkmcnt(0)" ::: "memory"); \
    __builtin_amdgcn_sched_barrier(0); \
} while (0)

// produce-compose LDS layout (R7)
#define PO_S   0
#define PO_F1  16
#define PO_F2T 32
#define PO_MT  48
#define PO_HM  64
// tree-compose LDS layout (R4)
#define TO_S   0
#define TO_SI  16
#define TO_F1  32
#define TO_F2T 48
#define TO_MT  64
#define TO_A1  80
#define TO_C1T 96
#define TO_B2T 112
#define TO_V4  128
#define TO_HM  132
#define GSTRIDE 152

// result blob at float offset 8192 (=+32 KB):
// [0]=LL, [1..64]=Ti[8][8], [65..68]=A[4]
#define WSR_OFF 8192

__device__ __forceinline__ float4 ld4(const float* p) {
    return *(const float4*)p;
}
__device__ __forceinline__ float dot4(float4 a, float4 b) {
    float s = a.x * b.x;
    s = fmaf(a.y, b.y, s);
    s = fmaf(a.z, b.z, s);
    s = fmaf(a.w, b.w, s);
    return s;
}
__device__ __forceinline__ float sel4(float x0, float x1, float x2, float x3, int k) {
    return (k == 0) ? x0 : ((k == 1) ? x1 : ((k == 2) ? x2 : x3));
}

struct Adj4 { float e[4][4]; };
__device__ __forceinline__ Adj4 adj4(const float4& Ra, const float4& Rb,
                                     const float4& Rc, const float4& Rd) {
    float sS[4][4];
    sS[0][0]=Ra.x; sS[0][1]=Ra.y; sS[0][2]=Ra.z; sS[0][3]=Ra.w;
    sS[1][0]=Rb.x; sS[1][1]=Rb.y; sS[1][2]=Rb.z; sS[1][3]=Rb.w;
    sS[2][0]=Rc.x; sS[2][1]=Rc.y; sS[2][2]=Rc.z; sS[2][3]=Rc.w;
    sS[3][0]=Rd.x; sS[3][1]=Rd.y; sS[3][2]=Rd.z; sS[3][3]=Rd.w;
    Adj4 A;
    #pragma unroll
    for (int a = 0; a < 4; ++a) {
        const int c0 = (a == 0) ? 1 : 0;
        const int c1 = (a <= 1) ? 2 : 1;
        const int c2 = (a <= 2) ? 3 : 2;
        #pragma unroll
        for (int b = 0; b < 4; ++b) {
            const int r0 = (b == 0) ? 1 : 0;
            const int r1 = (b <= 1) ? 2 : 1;
            const int r2 = (b <= 2) ? 3 : 2;
            float m00 = sS[r0][c0], m01 = sS[r0][c1], m02 = sS[r0][c2];
            float m10 = sS[r1][c0], m11 = sS[r1][c1], m12 = sS[r1][c2];
            float m20 = sS[r2][c0], m21 = sS[r2][c1], m22 = sS[r2][c2];
            float d0 = fmaf(m11, m22, -m12*m21);
            float d1 = fmaf(m10, m22, -m12*m20);
            float d2 = fmaf(m10, m21, -m11*m20);
            float det3 = m00*d0 - m01*d1 + m02*d2;
            A.e[a][b] = (((a + b) & 1) ? -det3 : det3);
        }
    }
    return A;
}
__device__ __forceinline__ float det4_colj(const Adj4& A, const float4& RJ, int j) {
    float a0j = sel4(A.e[0][0], A.e[0][1], A.e[0][2], A.e[0][3], j);
    float a1j = sel4(A.e[1][0], A.e[1][1], A.e[1][2], A.e[1][3], j);
    float a2j = sel4(A.e[2][0], A.e[2][1], A.e[2][2], A.e[2][3], j);
    float a3j = sel4(A.e[3][0], A.e[3][1], A.e[3][2], A.e[3][3], j);
    float t0 = RJ.x * a0j, t1 = RJ.y * a1j, t2 = RJ.z * a2j, t3 = RJ.w * a3j;
    return (t0 + t1) + (t2 + t3);
}

__device__ __forceinline__ LP init_lane(float x0, float x1, const Cn& C, int i, int j) {
    LP P;
    float v = 0.0f;
    if (i == j) v = (i < 2) ? C.qa : C.qc;
    if ((i ^ j) == 2) v = C.wa;
    P.jFF = v;
    v = 0.0f;
    if (j == (i & 1))     v = (i < 2) ? -C.qa : -C.wa;
    if (j == (i & 1) + 2) v = (i < 2) ? -C.qb : -C.wb;
    P.jFL = v;
    P.jFB = 0.0f;
    v = 0.0f;
    if (i == j) v = ((i < 2) ? C.qa : C.qc) + (((i & 1) == 0) ? 2.0f*C.ri : 0.0f);
    if ((i ^ j) == 2) v = C.qb;
    P.jLL = v;
    P.jLB = (((i == 0) && (j < 2)) || ((i == 2) && (j >= 2))) ? C.ri : 0.0f;
    P.jBB = (i == j) ? C.ri : 0.0f;
    P.hF = 0.0f;
    P.hL = ((j & 1) == 0) ? C.ri * (x0 + x1) : 0.0f;
    P.hB = C.ri * ((j & 1) ? x1 : x0);
    P.g  = -C.ri * (x0*x0 + x1*x1) + C.Cstep;
    P.dm = 1.0f; P.de = 0.0f;
    return P;
}

// ---- produce compose: one staging round + local full inverse (R7) ----
__device__ __forceinline__ LP compose_li(const LP& P1, const LP& P2, float* gl, int i, int j) {
    float hm = P1.hL + P2.hF;
    float Mb = P1.jLB + P2.jFB;
    float S  = P1.jLL + P2.jFF;
    float dm = P1.dm * P2.dm;
    float de = P1.de + P2.de;
    { int ex; dm = frexpf(dm, &ex); de += (float)ex; }
    const int ij = 4*i + j, ji = 4*j + i;

    gl[PO_S   + ij] = S;
    gl[PO_F1  + ij] = P1.jFL;
    gl[PO_F2T + ji] = P2.jFL;
    gl[PO_MT  + ji] = Mb;
    if (i == 0) gl[PO_HM + j] = hm;
    LGKM0();
    float4 Ra = ld4(gl + PO_S + 0);
    float4 Rb = ld4(gl + PO_S + 4);
    float4 Rc = ld4(gl + PO_S + 8);
    float4 Rd = ld4(gl + PO_S + 12);
    float4 RJ = ld4(gl + PO_S + 4*j);
    float4 f1r4 = ld4(gl + PO_F1  + 4*i);
    float4 f1T4 = ld4(gl + PO_F1  + 4*j);
    float4 f2c4 = ld4(gl + PO_F2T + 4*j);
    float4 f2T4 = ld4(gl + PO_F2T + 4*i);
    float4 mc4  = ld4(gl + PO_MT  + 4*j);
    float4 mT4  = ld4(gl + PO_MT  + 4*i);
    float4 hm4  = ld4(gl + PO_HM);

    Adj4 A = adj4(Ra, Rb, Rc, Rd);
    float det = det4_colj(A, RJ, j);
    dm *= det; { int ex; dm = frexpf(dm, &ex); de += (float)ex; }
    const float rdet = 1.0f / det;
    float4 sie0 = make_float4(A.e[0][0]*rdet, A.e[0][1]*rdet, A.e[0][2]*rdet, A.e[0][3]*rdet);
    float4 sie1 = make_float4(A.e[1][0]*rdet, A.e[1][1]*rdet, A.e[1][2]*rdet, A.e[1][3]*rdet);
    float4 sie2 = make_float4(A.e[2][0]*rdet, A.e[2][1]*rdet, A.e[2][2]*rdet, A.e[2][3]*rdet);
    float4 sie3 = make_float4(A.e[3][0]*rdet, A.e[3][1]*rdet, A.e[3][2]*rdet, A.e[3][3]*rdet);

    float4 a1r4 = make_float4(dot4(f1r4, sie0), dot4(f1r4, sie1),
                              dot4(f1r4, sie2), dot4(f1r4, sie3));
    float4 a1j4 = make_float4(dot4(f1T4, sie0), dot4(f1T4, sie1),
                              dot4(f1T4, sie2), dot4(f1T4, sie3));
    float4 c1c4 = make_float4(dot4(sie0, mc4), dot4(sie1, mc4),
                              dot4(sie2, mc4), dot4(sie3, mc4));
    float4 b2c4 = make_float4(dot4(sie0, f2c4), dot4(sie1, f2c4),
                              dot4(sie2, f2c4), dot4(sie3, f2c4));
    float4 v44  = make_float4(dot4(sie0, hm4), dot4(sie1, hm4),
                              dot4(sie2, hm4), dot4(sie3, hm4));

    LP R;
    R.jFF = P1.jFF - dot4(a1r4, f1T4);
    R.jFL = -dot4(a1r4, f2c4);
    R.jFB = P1.jFB - dot4(a1r4, mc4);
    R.jLL = P2.jLL - dot4(f2T4, b2c4);
    R.jLB = P2.jLB - dot4(f2T4, c1c4);
    R.jBB = P1.jBB + P2.jBB - dot4(mT4, c1c4);
    R.hF  = P1.hF - dot4(a1j4, hm4);
    R.hL  = P2.hL - dot4(f2c4, v44);
    R.hB  = P1.hB + P2.hB - dot4(mc4, v44);
    R.g   = P1.g + P2.g + 2.0f*(float)L2PI + 0.5f*dot4(hm4, v44);
    R.dm = dm; R.de = de;
    return R;
}

// ---- tree compose: 3-round staged (R4, verified bit-identical) ----
__device__ __forceinline__ LP compose_3r(const LP& P1, const LP& P2, float* gl, int i, int j) {
    float hm = P1.hL + P2.hF;
    float Mb = P1.jLB + P2.jFB;
    float S  = P1.jLL + P2.jFF;
    float dm = P1.dm * P2.dm;
    float de = P1.de + P2.de;
    { int ex; dm = frexpf(dm, &ex); de += (float)ex; }
    const int ij = 4*i + j, ji = 4*j + i;

    // round 1
    gl[TO_S   + ij] = S;
    gl[TO_F1  + ij] = P1.jFL;
    gl[TO_F2T + ji] = P2.jFL;
    gl[TO_MT  + ji] = Mb;
    if (i == 0) gl[TO_HM + j] = hm;
    LGKM0();

    const int r0 = (j == 0) ? 1 : 0;
    const int r1 = (j <= 1) ? 2 : 1;
    const int r2 = (j <= 2) ? 3 : 2;
    float4 R0 = ld4(gl + TO_S + 4*r0);
    float4 R1 = ld4(gl + TO_S + 4*r1);
    float4 R2 = ld4(gl + TO_S + 4*r2);
    float4 RJ = ld4(gl + TO_S + 4*j);
    float4 f1r4 = ld4(gl + TO_F1  + 4*i);
    float4 f1T4 = ld4(gl + TO_F1  + 4*j);
    float4 f2c4 = ld4(gl + TO_F2T + 4*j);
    float4 f2T4 = ld4(gl + TO_F2T + 4*i);
    float4 mc4  = ld4(gl + TO_MT  + 4*j);
    float4 mT4  = ld4(gl + TO_MT  + 4*i);
    float4 hm4  = ld4(gl + TO_HM);

    const bool i0 = (i == 0), i1 = (i <= 1), i2 = (i <= 2);
    float m00 = i0 ? R0.y : R0.x, m01 = i1 ? R0.z : R0.y, m02 = i2 ? R0.w : R0.z;
    float m10 = i0 ? R1.y : R1.x, m11 = i1 ? R1.z : R1.y, m12 = i2 ? R1.w : R1.z;
    float m20 = i0 ? R2.y : R2.x, m21 = i1 ? R2.z : R2.y, m22 = i2 ? R2.w : R2.z;
    float d0 = fmaf(m11, m22, -m12*m21);
    float d1 = fmaf(m10, m22, -m12*m20);
    float d2 = fmaf(m10, m21, -m11*m20);
    float det3 = m00*d0 - m01*d1 + m02*d2;
    float adj = (((i + j) & 1) ? -det3 : det3);
    float sji = (i < 2) ? (i0 ? RJ.x : RJ.y) : ((i == 2) ? RJ.z : RJ.w);
    float t = sji * adj;
    t += sx(t, 4); t += sx(t, 8);
    float det = t;
    dm *= det; { int ex; dm = frexpf(dm, &ex); de += (float)ex; }
    float Sio = adj * (1.0f / det);

    // round 2
    gl[TO_SI + ij] = Sio;
    LGKM0();
    float4 sr4 = ld4(gl + TO_SI + 4*i);
    float4 sc4 = ld4(gl + TO_SI + 4*j);

    float A1  = dot4(f1r4, sc4);
    float C1  = dot4(sr4,  mc4);
    float B2  = dot4(sr4,  f2c4);
    float v4i = dot4(sr4,  hm4);

    // round 3
    gl[TO_A1  + ij] = A1;
    gl[TO_C1T + ji] = C1;
    gl[TO_B2T + ji] = B2;
    if (i == j) gl[TO_V4 + i] = v4i;
    LGKM0();
    float4 a1r4 = ld4(gl + TO_A1  + 4*i);
    float4 a1j4 = ld4(gl + TO_A1  + 4*j);
    float4 c1c4 = ld4(gl + TO_C1T + 4*j);
    float4 b2c4 = ld4(gl + TO_B2T + 4*j);
    float4 v44  = ld4(gl + TO_V4);

    LP R;
    R.jFF = P1.jFF - dot4(a1r4, f1T4);
    R.jFL = -dot4(a1r4, f2c4);
    R.jFB = P1.jFB - dot4(a1r4, mc4);
    R.jLL = P2.jLL - dot4(f2T4, b2c4);
    R.jLB = P2.jLB - dot4(f2T4, c1c4);
    R.jBB = P1.jBB + P2.jBB - dot4(mT4, c1c4);
    R.hF  = P1.hF - dot4(a1j4, hm4);
    R.hL  = P2.hL - dot4(f2c4, v44);
    R.hB  = P1.hB + P2.hB - dot4(mc4, v44);
    R.g   = P1.g + P2.g + 2.0f*(float)L2PI + 0.5f*dot4(hm4, v44);
    R.dm = dm; R.de = de;
    return R;
}

__device__ __forceinline__ LP fetchx(const LP& P, int m) {
    LP O;
    O.jFF = sx(P.jFF,m); O.jFL = sx(P.jFL,m); O.jFB = sx(P.jFB,m);
    O.jLL = sx(P.jLL,m); O.jLB = sx(P.jLB,m); O.jBB = sx(P.jBB,m);
    O.hF  = sx(P.hF,m);  O.hL  = sx(P.hL,m);  O.hB  = sx(P.hB,m);
    O.g   = sx(P.g,m);   O.dm  = sx(P.dm,m);  O.de  = sx(P.de,m);
    return O;
}
__device__ __forceinline__ LP csel(bool up, const LP& O, const LP& P) {
    LP A;
    A.jFF = up?O.jFF:P.jFF; A.jFL = up?O.jFL:P.jFL; A.jFB = up?O.jFB:P.jFB;
    A.jLL = up?O.jLL:P.jLL; A.jLB = up?O.jLB:P.jLB; A.jBB = up?O.jBB:P.jBB;
    A.hF  = up?O.hF :P.hF;  A.hL  = up?O.hL :P.hL;  A.hB  = up?O.hB :P.hB;
    A.g   = up?O.g  :P.g;   A.dm  = up?O.dm :P.dm;  A.de  = up?O.de :P.de;
    return A;
}
__device__ __forceinline__ void pot_store(float* p, const LP& P) {
    p[0]=P.jFF; p[1]=P.jFL; p[2]=P.jFB; p[3]=P.jLL; p[4]=P.jLB; p[5]=P.jBB;
    p[6]=P.hF;  p[7]=P.hL;  p[8]=P.hB;  p[9]=P.g;   p[10]=P.dm; p[11]=P.de;
}
__device__ __forceinline__ LP pot_load(const float* p) {
    LP P;
    P.jFF=p[0]; P.jFL=p[1]; P.jFB=p[2]; P.jLL=p[3]; P.jLB=p[4]; P.jBB=p[5];
    P.hF=p[6];  P.hL=p[7];  P.hB=p[8];  P.g=p[9];   P.dm=p[10]; P.de=p[11];
    return P;
}
__device__ __forceinline__ void pot_store4(float* p, const LP& P) {
    *(float4*)(p + 0) = make_float4(P.jFF, P.jFL, P.jFB, P.jLL);
    *(float4*)(p + 4) = make_float4(P.jLB, P.jBB, P.hF,  P.hL);
    *(float4*)(p + 8) = make_float4(P.hB,  P.g,   P.dm,  P.de);
}
__device__ __forceinline__ LP pot_load4(const float* p) {
    float4 a = ld4(p + 0), b = ld4(p + 4), c = ld4(p + 8);
    LP P;
    P.jFF=a.x; P.jFL=a.y; P.jFB=a.z; P.jLL=a.w;
    P.jLB=b.x; P.jBB=b.y; P.hF=b.z;  P.hL=b.w;
    P.hB=c.x;  P.g=c.y;   P.dm=c.z;  P.de=c.w;
    return P;
}

// ---------- Kernel 1: produce.  32 blocks x 512 threads. ----------
__global__ __launch_bounds__(512)
void hmm_produce(const float* __restrict__ track,
                 const float* __restrict__ obs_noise_p,
                 const float* __restrict__ trans_noise_p,
                 float* __restrict__ ws)
{
    __shared__ float pool[2][8][16][13];
    __shared__ __align__(16) float cbuf[32 * GSTRIDE];
    const int tid = (int)threadIdx.x;
    const int l = tid & 63, w = tid >> 6;
    const int i = (l >> 2) & 3, j = l & 3, g = (l >> 4) & 3;
    const int gid = w * 4 + g;
    float* gl = &cbuf[(size_t)gid * GSTRIDE];
    const int bid = (int)blockIdx.x;

    const double sg2d = (double)obs_noise_p[0] * (double)obs_noise_p[0];
    const double qn2d = (double)trans_noise_p[0] * (double)trans_noise_p[0];

    Cn C;
    C.qa = (float)(12.0/qn2d); C.qb = (float)(-6.0/qn2d); C.qc = (float)(4.0/qn2d);
    C.wa = (float)(6.0/qn2d);  C.wb = (float)(-2.0/qn2d);
    C.ri = (float)(32.0/sg2d);
    C.Cstep = (float)(-2.0*log(2.0*M_PI*sg2d/32.0) - 2.0*L2PI
                      - 0.5*(4.0*log(qn2d) - 2.0*log(12.0)));

    const int t0 = (bid * 32 + gid) * 2;
    LP P;
    #pragma unroll 1
    for (int op = 0; op < 6; ++op) {
        LP A, Bp;
        if (op == 0) {
            A  = init_lane(track[2*t0+0], track[2*t0+1], C, i, j);
            Bp = init_lane(track[2*t0+2], track[2*t0+3], C, i, j);
        } else if (op < 3) {
            const int m = 16 << (op - 1);
            LP O = fetchx(P, m);
            const bool up = (l & m) != 0;
            A  = csel(up, O, P);
            Bp = csel(up, P, O);
        } else {
            const int s = 1 << (op - 3);
            const int buf = (op - 3) & 1;
            if (l < 16) pot_store(&pool[buf][w][l][0], P);
            __syncthreads();
            LP O = pot_load(&pool[buf][w ^ s][l & 15][0]);
            const bool up = (w & s) != 0;
            A  = csel(up, O, P);
            Bp = csel(up, P, O);
        }
        P = compose_li(A, Bp, gl, i, j);
    }
    if (w == 0 && l < 16)
        pot_store4(ws + ((size_t)bid * 16 + l) * 12, P);
}

// ---------- Kernel 2: tree.  1 block x 512 threads.
// 5 composes (3-round staged) + shuffle final; writes 69-float blob. ----------
__global__ __launch_bounds__(512)
void hmm_tree(const float* __restrict__ bias_scales,
              const float* __restrict__ obs_noise_p,
              float* __restrict__ ws)
{
    __shared__ float pool[2][8][16][13];
    __shared__ __align__(16) float cbuf[32 * GSTRIDE];
    const int tid = (int)threadIdx.x;
    const int l = tid & 63, w = tid >> 6;
    const int i = (l >> 2) & 3, j = l & 3, gb = l & 48, g = (l >> 4) & 3;
    const int gid = w * 4 + g;
    float* gl = &cbuf[(size_t)gid * GSTRIDE];
    float* wsr = ws + WSR_OFF;

    // hoisted input-only constants (identical expression trees -> identical
    // values); f64 logs overlap the cold pot loads
    const double sg2d = (double)obs_noise_p[0] * (double)obs_noise_p[0];
    const double a00 = (double)bias_scales[0];
    const double a01 = (double)bias_scales[1];
    const double Td = 2048.0;
    const double c0d = sg2d/a00, c1d = sg2d/a01;
    const double llconst = -31.0*(Td*(L2PI + log(sg2d)) + log((c0d+Td)/c0d))
                           -31.0*(Td*(L2PI + log(sg2d)) + log((c1d+Td)/c1d))
                           -2.0*Td*log(32.0);
    const float gconst = (float)(-4.0*L2PI + 2.0*log(32.0) - log(a00) - log(a01));

    LP P = pot_load4(ws + ((size_t)gid * 16 + (l & 15)) * 12);
    #pragma unroll 1
    for (int op = 0; op < 5; ++op) {
        LP A, Bp;
        if (op < 2) {
            const int m = 16 << op;
            LP O = fetchx(P, m);
            const bool up = (l & m) != 0;
            A  = csel(up, O, P);
            Bp = csel(up, P, O);
        } else {
            const int s = 1 << (op - 2);
            const int buf = (op - 2) & 1;
            if (l < 16) pot_store(&pool[buf][w][l][0], P);
            __syncthreads();
            LP O = pot_load(&pool[buf][w ^ s][l & 15][0]);
            const bool up = (w & s) != 0;
            A  = csel(up, O, P);
            Bp = csel(up, P, O);
        }
        P = compose_3r(A, Bp, gl, i, j);
    }

    // ---------- final stage on wave 0 (R4 shuffle version, verified) ----------
    if (w == 0) {
        const float a0i = (float)((i & 1) ? a01 : a00);
        P.jFF += (i == j) ? 1.0f : 0.0f;
        P.jBB += (i == j) ? 32.0f / a0i : 0.0f;
        P.g   += gconst;
        float dm = P.dm, de = P.de;
        // marginalize z0: adjugate inverse of jFF
        float S = P.jFF;
        const int r0 = (j == 0) ? 1 : 0;
        const int r1 = (j <= 1) ? 2 : 1;
        const int r2 = (j <= 2) ? 3 : 2;
        const int c0 = (i == 0) ? 1 : 0;
        const int c1 = (i <= 1) ? 2 : 1;
        const int c2 = (i <= 2) ? 3 : 2;
        float m00 = shf(S, gb + 4*r0 + c0), m01 = shf(S, gb + 4*r0 + c1), m02 = shf(S, gb + 4*r0 + c2);
        float m10 = shf(S, gb + 4*r1 + c0), m11 = shf(S, gb + 4*r1 + c1), m12 = shf(S, gb + 4*r1 + c2);
        float m20 = shf(S, gb + 4*r2 + c0), m21 = shf(S, gb + 4*r2 + c1), m22 = shf(S, gb + 4*r2 + c2);
        float d0 = fmaf(m11, m22, -m12*m21);
        float d1 = fmaf(m10, m22, -m12*m20);
        float d2 = fmaf(m10, m21, -m11*m20);
        float det3 = m00*d0 - m01*d1 + m02*d2;
        float adj = (((i + j) & 1) ? -det3 : det3);
        float sji = shf(S, gb + 4*j + i);
        float tdet = sji * adj;
        tdet += sx(tdet, 4); tdet += sx(tdet, 8);
        float det = tdet;
        dm *= det; { int ex; dm = frexpf(dm, &ex); de += (float)ex; }
        const float Si = adj * (1.0f / det);
        float sr[4], fr[4], fT[4], bc[4], bT[4], hfc[4];
        #pragma unroll
        for (int r = 0; r < 4; ++r) {
            sr[r]  = shf(Si, gb + 4*i + r);
            fr[r]  = shf(P.jFL, gb + 4*r + i);
            fT[r]  = shf(P.jFL, gb + 4*r + j);
            bc[r]  = shf(P.jFB, gb + 4*r + i);
            bT[r]  = shf(P.jFB, gb + 4*r + j);
            hfc[r] = shf(P.hF, gb + 5*r);
        }
        float YL = 0.0f, YB = 0.0f, yFi = 0.0f;
        #pragma unroll
        for (int r = 0; r < 4; ++r) {
            YL  = fmaf(sr[r], fT[r], YL);
            YB  = fmaf(sr[r], bT[r], YB);
            yFi = fmaf(sr[r], hfc[r], yFi);
        }
        float ylc[4], ybc[4], yfc[4];
        #pragma unroll
        for (int r = 0; r < 4; ++r) {
            ylc[r] = shf(YL, gb + 4*r + j);
            ybc[r] = shf(YB, gb + 4*r + j);
            yfc[r] = shf(yFi, gb + 5*r);
        }
        float s1 = 0.0f, s2 = 0.0f, s3 = 0.0f, sh1 = 0.0f, sh2 = 0.0f, qF = 0.0f;
        #pragma unroll
        for (int r = 0; r < 4; ++r) {
            s1  = fmaf(fr[r], ylc[r], s1);
            s2  = fmaf(fr[r], ybc[r], s2);
            s3  = fmaf(bc[r], ybc[r], s3);
            sh1 = fmaf(fT[r], yfc[r], sh1);
            sh2 = fmaf(bT[r], yfc[r], sh2);
            qF  = fmaf(hfc[r], yfc[r], qF);
        }
        float J8ss = P.jLL - s1;
        float J8sb = P.jLB - s2;
        float J8bb = P.jBB - s3;
        float h8s  = P.hL - sh1;
        float h8b  = P.hB - sh2;
        float g8   = P.g + 2.0f*(float)L2PI + 0.5f*qF;

        // 8x8 stage across all 64 lanes: lane = (I,J)
        const int I = l >> 3, J = l & 7, i4 = I & 3, j4 = J & 3;
        float ss  = shf(J8ss, 4*i4 + j4);
        float sb  = shf(J8sb, 4*i4 + j4);
        float sbT = shf(J8sb, 4*j4 + i4);
        float bb  = shf(J8bb, 4*i4 + j4);
        float A8 = (I < 4) ? ((J < 4) ? ss : sb) : ((J < 4) ? sbT : bb);
        const float J8sav = A8;
        float h8v = (J < 4) ? shf(h8s, j4) : shf(h8b, j4);
        float h8r = (I < 4) ? shf(h8s, i4) : shf(h8b, i4);
        float K8 = (I == J) ? 1.0f : 0.0f;
        #pragma unroll 1
        for (int p = 0; p < 8; ++p) {
            float piv = shf(A8, 9*p);
            dm *= piv; { int ex; dm = frexpf(dm, &ex); de += (float)ex; }
            float ip = 1.0f / piv;
            float Ap = shf(A8, 8*p + J) * ip;
            float Kp = shf(K8, 8*p + J) * ip;
            float f  = shf(A8, 8*I + p);
            bool isp = (I == p);
            A8 = isp ? A8 * ip : fmaf(-f, Ap, A8);
            K8 = isp ? K8 * ip : fmaf(-f, Kp, K8);
        }
        float tq = h8r * K8 * h8v;
        tq += sx(tq,1); tq += sx(tq,2); tq += sx(tq,4);
        tq += sx(tq,8); tq += sx(tq,16); tq += sx(tq,32);

        double ll = (double)g8 + 4.0*L2PI
                    - 0.5*(log((double)dm) + (double)de*LN2) + 0.5*(double)tq;
        ll += llconst;

        const float i32 = 1.0f/32.0f, irn = 0.176776695296637f;
        int a = (I >= 4) ? I - 4 : I + 4;
        int b = (J >= 4) ? J - 4 : J + 4;
        float scale = (I >= 4 && J >= 4) ? i32 : (((I >= 4) != (J >= 4)) ? irn : 1.0f);
        wsr[1 + 8*a + b] = J8sav * scale;
        if (l < 4) {
            double a0k = (l & 1) ? a01 : a00;
            wsr[65 + l] = (float)(a0k*sg2d/(sg2d + Td*a0k));
        }
        if (l == 0) wsr[0] = (float)ll;
    }
}

// ---------- Kernel 3: expand.  69 blocks x 256 threads, fully parallel. ----
__global__ __launch_bounds__(256)
void hmm_expand(const float* __restrict__ wsr,
                float* __restrict__ out)
{
    const int idx = (int)blockIdx.x * 256 + (int)threadIdx.x;
    const int total = 1 + 132*132;
    if (idx >= total) return;
    const float inv32 = 1.0f/32.0f;
    const float invrn = 0.176776695296637f;
    float v;
    if (idx == 0) {
        v = wsr[0];
    } else {
        int el = idx - 1;
        int r = el / 132;
        int cc = el - 132*r;
        if (r < 128) {
            int ki = ((r >> 6) << 1) | (r & 1);
            if (cc < 128) {
                int kj = ((cc >> 6) << 1) | (cc & 1);
                v = wsr[1 + 8*ki + kj] * inv32;
                if (ki == kj) {
                    float ia = 1.0f / wsr[65 + ki];
                    v -= ia * inv32;
                    if (r == cc) v += ia;
                }
            } else {
                v = wsr[1 + 8*ki + (cc - 124)] * invrn;
            }
        } else {
            if (cc < 128) {
                int kj = ((cc >> 6) << 1) | (cc & 1);
                v = wsr[1 + 8*kj + (r - 124)] * invrn;
            } else {
                v = wsr[1 + 8*(r - 124) + (cc - 124)];
            }
        }
    }
    out[idx] = v;
}

extern "C" void kernel_launch(void* const* d_in, const int* in_sizes, int n_in,
                              void* d_out, int out_size, void* d_ws, size_t ws_size,
                              hipStream_t stream) {
    (void)in_sizes; (void)n_in; (void)out_size; (void)ws_size;
    const float* track       = (const float*)d_in[0];
    const float* bias_scales = (const float*)d_in[1];
    const float* obs_noise   = (const float*)d_in[2];
    const float* trans_noise = (const float*)d_in[3];
    float* out = (float*)d_out;
    float* ws  = (float*)d_ws;   // pots 24 KB; result blob at +32 KB
    hipLaunchKernelGGL(hmm_produce, dim3(32), dim3(512), 0, stream,
                       track, obs_noise, trans_noise, ws);
    hipLaunchKernelGGL(hmm_tree, dim3(1), dim3(512), 0, stream,
                       bias_scales, obs_noise, ws);
    hipLaunchKernelGGL(hmm_expand, dim3(69), dim3(256), 0, stream,
                       (const float*)(ws + WSR_OFF), out);
}

// Round 10
// 80.737 us; speedup vs baseline: 1.1498x; 1.0077x over previous
//
#include <hip/hip_runtime.h>
#include <math.h>

#define L2PI 1.8378770664093454835606594728112
#define LN2  0.69314718055994530941723212145818

// ---------------------------------------------------------------------------
// Lane-parallel Gaussian potential (fp32) over (F = first state(4),
// L = last state(4), B = class-bias means(4)).  16 lanes per potential.
//
// Round 10: 2 dispatches.
//  - produce (32 blk): local-inverse compose (R7/R9 verified), 64 steps/blk.
//  - tail (35 blk): EVERY block redundantly runs the identical 5-compose
//    tree (3-round staged, R9) + shuffle final -> LDS blob, then writes its
//    512-element output slice.  Redundant compute is deterministic and free
//    (those CUs were idle); removes one dispatch boundary + the global blob
//    round-trip.  All math bit-identical to harness-verified R9.
// ---------------------------------------------------------------------------
struct LP {
    float jFF, jFL, jFB, jLL, jLB, jBB;
    float hF, hL, hB, g, dm, de;
};

struct Cn { float qa, qb, qc, wa, wb, ri, Cstep; };

__device__ __forceinline__ float shf(float v, int s) { return __shfl(v, s, 64); }
__device__ __forceinline__ float sx (float v, int m) { return __shfl_xor(v, m, 64); }

#define LGKM0() do { \
    asm volatile("s_waitcnt lgkmcnt(0)" ::: "memory"); \
    __builtin_amdgcn_sched_barrier(0); \
} while (0)

// produce-compose LDS layout (R7)
#define PO_S   0
#define PO_F1  16
#define PO_F2T 32
#define PO_MT  48
#define PO_HM  64
// tree-compose LDS layout (R4)
#define TO_S   0
#define TO_SI  16
#define TO_F1  32
#define TO_F2T 48
#define TO_MT  64
#define TO_A1  80
#define TO_C1T 96
#define TO_B2T 112
#define TO_V4  128
#define TO_HM  132
#define GSTRIDE 152

__device__ __forceinline__ float4 ld4(const float* p) {
    return *(const float4*)p;
}
__device__ __forceinline__ float dot4(float4 a, float4 b) {
    float s = a.x * b.x;
    s = fmaf(a.y, b.y, s);
    s = fmaf(a.z, b.z, s);
    s = fmaf(a.w, b.w, s);
    return s;
}
__device__ __forceinline__ float sel4(float x0, float x1, float x2, float x3, int k) {
    return (k == 0) ? x0 : ((k == 1) ? x1 : ((k == 2) ? x2 : x3));
}

struct Adj4 { float e[4][4]; };
__device__ __forceinline__ Adj4 adj4(const float4& Ra, const float4& Rb,
                                     const float4& Rc, const float4& Rd) {
    float sS[4][4];
    sS[0][0]=Ra.x; sS[0][1]=Ra.y; sS[0][2]=Ra.z; sS[0][3]=Ra.w;
    sS[1][0]=Rb.x; sS[1][1]=Rb.y; sS[1][2]=Rb.z; sS[1][3]=Rb.w;
    sS[2][0]=Rc.x; sS[2][1]=Rc.y; sS[2][2]=Rc.z; sS[2][3]=Rc.w;
    sS[3][0]=Rd.x; sS[3][1]=Rd.y; sS[3][2]=Rd.z; sS[3][3]=Rd.w;
    Adj4 A;
    #pragma unroll
    for (int a = 0; a < 4; ++a) {
        const int c0 = (a == 0) ? 1 : 0;
        const int c1 = (a <= 1) ? 2 : 1;
        const int c2 = (a <= 2) ? 3 : 2;
        #pragma unroll
        for (int b = 0; b < 4; ++b) {
            const int r0 = (b == 0) ? 1 : 0;
            const int r1 = (b <= 1) ? 2 : 1;
            const int r2 = (b <= 2) ? 3 : 2;
            float m00 = sS[r0][c0], m01 = sS[r0][c1], m02 = sS[r0][c2];
            float m10 = sS[r1][c0], m11 = sS[r1][c1], m12 = sS[r1][c2];
            float m20 = sS[r2][c0], m21 = sS[r2][c1], m22 = sS[r2][c2];
            float d0 = fmaf(m11, m22, -m12*m21);
            float d1 = fmaf(m10, m22, -m12*m20);
            float d2 = fmaf(m10, m21, -m11*m20);
            float det3 = m00*d0 - m01*d1 + m02*d2;
            A.e[a][b] = (((a + b) & 1) ? -det3 : det3);
        }
    }
    return A;
}
__device__ __forceinline__ float det4_colj(const Adj4& A, const float4& RJ, int j) {
    float a0j = sel4(A.e[0][0], A.e[0][1], A.e[0][2], A.e[0][3], j);
    float a1j = sel4(A.e[1][0], A.e[1][1], A.e[1][2], A.e[1][3], j);
    float a2j = sel4(A.e[2][0], A.e[2][1], A.e[2][2], A.e[2][3], j);
    float a3j = sel4(A.e[3][0], A.e[3][1], A.e[3][2], A.e[3][3], j);
    float t0 = RJ.x * a0j, t1 = RJ.y * a1j, t2 = RJ.z * a2j, t3 = RJ.w * a3j;
    return (t0 + t1) + (t2 + t3);
}

__device__ __forceinline__ LP init_lane(float x0, float x1, const Cn& C, int i, int j) {
    LP P;
    float v = 0.0f;
    if (i == j) v = (i < 2) ? C.qa : C.qc;
    if ((i ^ j) == 2) v = C.wa;
    P.jFF = v;
    v = 0.0f;
    if (j == (i & 1))     v = (i < 2) ? -C.qa : -C.wa;
    if (j == (i & 1) + 2) v = (i < 2) ? -C.qb : -C.wb;
    P.jFL = v;
    P.jFB = 0.0f;
    v = 0.0f;
    if (i == j) v = ((i < 2) ? C.qa : C.qc) + (((i & 1) == 0) ? 2.0f*C.ri : 0.0f);
    if ((i ^ j) == 2) v = C.qb;
    P.jLL = v;
    P.jLB = (((i == 0) && (j < 2)) || ((i == 2) && (j >= 2))) ? C.ri : 0.0f;
    P.jBB = (i == j) ? C.ri : 0.0f;
    P.hF = 0.0f;
    P.hL = ((j & 1) == 0) ? C.ri * (x0 + x1) : 0.0f;
    P.hB = C.ri * ((j & 1) ? x1 : x0);
    P.g  = -C.ri * (x0*x0 + x1*x1) + C.Cstep;
    P.dm = 1.0f; P.de = 0.0f;
    return P;
}

// ---- produce compose: one staging round + local full inverse (R7) ----
__device__ __forceinline__ LP compose_li(const LP& P1, const LP& P2, float* gl, int i, int j) {
    float hm = P1.hL + P2.hF;
    float Mb = P1.jLB + P2.jFB;
    float S  = P1.jLL + P2.jFF;
    float dm = P1.dm * P2.dm;
    float de = P1.de + P2.de;
    { int ex; dm = frexpf(dm, &ex); de += (float)ex; }
    const int ij = 4*i + j, ji = 4*j + i;

    gl[PO_S   + ij] = S;
    gl[PO_F1  + ij] = P1.jFL;
    gl[PO_F2T + ji] = P2.jFL;
    gl[PO_MT  + ji] = Mb;
    if (i == 0) gl[PO_HM + j] = hm;
    LGKM0();
    float4 Ra = ld4(gl + PO_S + 0);
    float4 Rb = ld4(gl + PO_S + 4);
    float4 Rc = ld4(gl + PO_S + 8);
    float4 Rd = ld4(gl + PO_S + 12);
    float4 RJ = ld4(gl + PO_S + 4*j);
    float4 f1r4 = ld4(gl + PO_F1  + 4*i);
    float4 f1T4 = ld4(gl + PO_F1  + 4*j);
    float4 f2c4 = ld4(gl + PO_F2T + 4*j);
    float4 f2T4 = ld4(gl + PO_F2T + 4*i);
    float4 mc4  = ld4(gl + PO_MT  + 4*j);
    float4 mT4  = ld4(gl + PO_MT  + 4*i);
    float4 hm4  = ld4(gl + PO_HM);

    Adj4 A = adj4(Ra, Rb, Rc, Rd);
    float det = det4_colj(A, RJ, j);
    dm *= det; { int ex; dm = frexpf(dm, &ex); de += (float)ex; }
    const float rdet = 1.0f / det;
    float4 sie0 = make_float4(A.e[0][0]*rdet, A.e[0][1]*rdet, A.e[0][2]*rdet, A.e[0][3]*rdet);
    float4 sie1 = make_float4(A.e[1][0]*rdet, A.e[1][1]*rdet, A.e[1][2]*rdet, A.e[1][3]*rdet);
    float4 sie2 = make_float4(A.e[2][0]*rdet, A.e[2][1]*rdet, A.e[2][2]*rdet, A.e[2][3]*rdet);
    float4 sie3 = make_float4(A.e[3][0]*rdet, A.e[3][1]*rdet, A.e[3][2]*rdet, A.e[3][3]*rdet);

    float4 a1r4 = make_float4(dot4(f1r4, sie0), dot4(f1r4, sie1),
                              dot4(f1r4, sie2), dot4(f1r4, sie3));
    float4 a1j4 = make_float4(dot4(f1T4, sie0), dot4(f1T4, sie1),
                              dot4(f1T4, sie2), dot4(f1T4, sie3));
    float4 c1c4 = make_float4(dot4(sie0, mc4), dot4(sie1, mc4),
                              dot4(sie2, mc4), dot4(sie3, mc4));
    float4 b2c4 = make_float4(dot4(sie0, f2c4), dot4(sie1, f2c4),
                              dot4(sie2, f2c4), dot4(sie3, f2c4));
    float4 v44  = make_float4(dot4(sie0, hm4), dot4(sie1, hm4),
                              dot4(sie2, hm4), dot4(sie3, hm4));

    LP R;
    R.jFF = P1.jFF - dot4(a1r4, f1T4);
    R.jFL = -dot4(a1r4, f2c4);
    R.jFB = P1.jFB - dot4(a1r4, mc4);
    R.jLL = P2.jLL - dot4(f2T4, b2c4);
    R.jLB = P2.jLB - dot4(f2T4, c1c4);
    R.jBB = P1.jBB + P2.jBB - dot4(mT4, c1c4);
    R.hF  = P1.hF - dot4(a1j4, hm4);
    R.hL  = P2.hL - dot4(f2c4, v44);
    R.hB  = P1.hB + P2.hB - dot4(mc4, v44);
    R.g   = P1.g + P2.g + 2.0f*(float)L2PI + 0.5f*dot4(hm4, v44);
    R.dm = dm; R.de = de;
    return R;
}

// ---- tree compose: 3-round staged (R4/R9, verified bit-identical) ----
__device__ __forceinline__ LP compose_3r(const LP& P1, const LP& P2, float* gl, int i, int j) {
    float hm = P1.hL + P2.hF;
    float Mb = P1.jLB + P2.jFB;
    float S  = P1.jLL + P2.jFF;
    float dm = P1.dm * P2.dm;
    float de = P1.de + P2.de;
    { int ex; dm = frexpf(dm, &ex); de += (float)ex; }
    const int ij = 4*i + j, ji = 4*j + i;

    // round 1
    gl[TO_S   + ij] = S;
    gl[TO_F1  + ij] = P1.jFL;
    gl[TO_F2T + ji] = P2.jFL;
    gl[TO_MT  + ji] = Mb;
    if (i == 0) gl[TO_HM + j] = hm;
    LGKM0();

    const int r0 = (j == 0) ? 1 : 0;
    const int r1 = (j <= 1) ? 2 : 1;
    const int r2 = (j <= 2) ? 3 : 2;
    float4 R0 = ld4(gl + TO_S + 4*r0);
    float4 R1 = ld4(gl + TO_S + 4*r1);
    float4 R2 = ld4(gl + TO_S + 4*r2);
    float4 RJ = ld4(gl + TO_S + 4*j);
    float4 f1r4 = ld4(gl + TO_F1  + 4*i);
    float4 f1T4 = ld4(gl + TO_F1  + 4*j);
    float4 f2c4 = ld4(gl + TO_F2T + 4*j);
    float4 f2T4 = ld4(gl + TO_F2T + 4*i);
    float4 mc4  = ld4(gl + TO_MT  + 4*j);
    float4 mT4  = ld4(gl + TO_MT  + 4*i);
    float4 hm4  = ld4(gl + TO_HM);

    const bool i0 = (i == 0), i1 = (i <= 1), i2 = (i <= 2);
    float m00 = i0 ? R0.y : R0.x, m01 = i1 ? R0.z : R0.y, m02 = i2 ? R0.w : R0.z;
    float m10 = i0 ? R1.y : R1.x, m11 = i1 ? R1.z : R1.y, m12 = i2 ? R1.w : R1.z;
    float m20 = i0 ? R2.y : R2.x, m21 = i1 ? R2.z : R2.y, m22 = i2 ? R2.w : R2.z;
    float d0 = fmaf(m11, m22, -m12*m21);
    float d1 = fmaf(m10, m22, -m12*m20);
    float d2 = fmaf(m10, m21, -m11*m20);
    float det3 = m00*d0 - m01*d1 + m02*d2;
    float adj = (((i + j) & 1) ? -det3 : det3);
    float sji = (i < 2) ? (i0 ? RJ.x : RJ.y) : ((i == 2) ? RJ.z : RJ.w);
    float t = sji * adj;
    t += sx(t, 4); t += sx(t, 8);
    float det = t;
    dm *= det; { int ex; dm = frexpf(dm, &ex); de += (float)ex; }
    float Sio = adj * (1.0f / det);

    // round 2
    gl[TO_SI + ij] = Sio;
    LGKM0();
    float4 sr4 = ld4(gl + TO_SI + 4*i);
    float4 sc4 = ld4(gl + TO_SI + 4*j);

    float A1  = dot4(f1r4, sc4);
    float C1  = dot4(sr4,  mc4);
    float B2  = dot4(sr4,  f2c4);
    float v4i = dot4(sr4,  hm4);

    // round 3
    gl[TO_A1  + ij] = A1;
    gl[TO_C1T + ji] = C1;
    gl[TO_B2T + ji] = B2;
    if (i == j) gl[TO_V4 + i] = v4i;
    LGKM0();
    float4 a1r4 = ld4(gl + TO_A1  + 4*i);
    float4 a1j4 = ld4(gl + TO_A1  + 4*j);
    float4 c1c4 = ld4(gl + TO_C1T + 4*j);
    float4 b2c4 = ld4(gl + TO_B2T + 4*j);
    float4 v44  = ld4(gl + TO_V4);

    LP R;
    R.jFF = P1.jFF - dot4(a1r4, f1T4);
    R.jFL = -dot4(a1r4, f2c4);
    R.jFB = P1.jFB - dot4(a1r4, mc4);
    R.jLL = P2.jLL - dot4(f2T4, b2c4);
    R.jLB = P2.jLB - dot4(f2T4, c1c4);
    R.jBB = P1.jBB + P2.jBB - dot4(mT4, c1c4);
    R.hF  = P1.hF - dot4(a1j4, hm4);
    R.hL  = P2.hL - dot4(f2c4, v44);
    R.hB  = P1.hB + P2.hB - dot4(mc4, v44);
    R.g   = P1.g + P2.g + 2.0f*(float)L2PI + 0.5f*dot4(hm4, v44);
    R.dm = dm; R.de = de;
    return R;
}

__device__ __forceinline__ LP fetchx(const LP& P, int m) {
    LP O;
    O.jFF = sx(P.jFF,m); O.jFL = sx(P.jFL,m); O.jFB = sx(P.jFB,m);
    O.jLL = sx(P.jLL,m); O.jLB = sx(P.jLB,m); O.jBB = sx(P.jBB,m);
    O.hF  = sx(P.hF,m);  O.hL  = sx(P.hL,m);  O.hB  = sx(P.hB,m);
    O.g   = sx(P.g,m);   O.dm  = sx(P.dm,m);  O.de  = sx(P.de,m);
    return O;
}
__device__ __forceinline__ LP csel(bool up, const LP& O, const LP& P) {
    LP A;
    A.jFF = up?O.jFF:P.jFF; A.jFL = up?O.jFL:P.jFL; A.jFB = up?O.jFB:P.jFB;
    A.jLL = up?O.jLL:P.jLL; A.jLB = up?O.jLB:P.jLB; A.jBB = up?O.jBB:P.jBB;
    A.hF  = up?O.hF :P.hF;  A.hL  = up?O.hL :P.hL;  A.hB  = up?O.hB :P.hB;
    A.g   = up?O.g  :P.g;   A.dm  = up?O.dm :P.dm;  A.de  = up?O.de :P.de;
    return A;
}
__device__ __forceinline__ void pot_store(float* p, const LP& P) {
    p[0]=P.jFF; p[1]=P.jFL; p[2]=P.jFB; p[3]=P.jLL; p[4]=P.jLB; p[5]=P.jBB;
    p[6]=P.hF;  p[7]=P.hL;  p[8]=P.hB;  p[9]=P.g;   p[10]=P.dm; p[11]=P.de;
}
__device__ __forceinline__ LP pot_load(const float* p) {
    LP P;
    P.jFF=p[0]; P.jFL=p[1]; P.jFB=p[2]; P.jLL=p[3]; P.jLB=p[4]; P.jBB=p[5];
    P.hF=p[6];  P.hL=p[7];  P.hB=p[8];  P.g=p[9];   P.dm=p[10]; P.de=p[11];
    return P;
}
__device__ __forceinline__ void pot_store4(float* p, const LP& P) {
    *(float4*)(p + 0) = make_float4(P.jFF, P.jFL, P.jFB, P.jLL);
    *(float4*)(p + 4) = make_float4(P.jLB, P.jBB, P.hF,  P.hL);
    *(float4*)(p + 8) = make_float4(P.hB,  P.g,   P.dm,  P.de);
}
__device__ __forceinline__ LP pot_load4(const float* p) {
    float4 a = ld4(p + 0), b = ld4(p + 4), c = ld4(p + 8);
    LP P;
    P.jFF=a.x; P.jFL=a.y; P.jFB=a.z; P.jLL=a.w;
    P.jLB=b.x; P.jBB=b.y; P.hF=b.z;  P.hL=b.w;
    P.hB=c.x;  P.g=c.y;   P.dm=c.z;  P.de=c.w;
    return P;
}

// ---------- Kernel 1: produce.  32 blocks x 512 threads. ----------
__global__ __launch_bounds__(512)
void hmm_produce(const float* __restrict__ track,
                 const float* __restrict__ obs_noise_p,
                 const float* __restrict__ trans_noise_p,
                 float* __restrict__ ws)
{
    __shared__ float pool[2][8][16][13];
    __shared__ __align__(16) float cbuf[32 * GSTRIDE];
    const int tid = (int)threadIdx.x;
    const int l = tid & 63, w = tid >> 6;
    const int i = (l >> 2) & 3, j = l & 3, g = (l >> 4) & 3;
    const int gid = w * 4 + g;
    float* gl = &cbuf[(size_t)gid * GSTRIDE];
    const int bid = (int)blockIdx.x;

    const double sg2d = (double)obs_noise_p[0] * (double)obs_noise_p[0];
    const double qn2d = (double)trans_noise_p[0] * (double)trans_noise_p[0];

    Cn C;
    C.qa = (float)(12.0/qn2d); C.qb = (float)(-6.0/qn2d); C.qc = (float)(4.0/qn2d);
    C.wa = (float)(6.0/qn2d);  C.wb = (float)(-2.0/qn2d);
    C.ri = (float)(32.0/sg2d);
    C.Cstep = (float)(-2.0*log(2.0*M_PI*sg2d/32.0) - 2.0*L2PI
                      - 0.5*(4.0*log(qn2d) - 2.0*log(12.0)));

    const int t0 = (bid * 32 + gid) * 2;
    LP P;
    #pragma unroll 1
    for (int op = 0; op < 6; ++op) {
        LP A, Bp;
        if (op == 0) {
            A  = init_lane(track[2*t0+0], track[2*t0+1], C, i, j);
            Bp = init_lane(track[2*t0+2], track[2*t0+3], C, i, j);
        } else if (op < 3) {
            const int m = 16 << (op - 1);
            LP O = fetchx(P, m);
            const bool up = (l & m) != 0;
            A  = csel(up, O, P);
            Bp = csel(up, P, O);
        } else {
            const int s = 1 << (op - 3);
            const int buf = (op - 3) & 1;
            if (l < 16) pot_store(&pool[buf][w][l][0], P);
            __syncthreads();
            LP O = pot_load(&pool[buf][w ^ s][l & 15][0]);
            const bool up = (w & s) != 0;
            A  = csel(up, O, P);
            Bp = csel(up, P, O);
        }
        P = compose_li(A, Bp, gl, i, j);
    }
    if (w == 0 && l < 16)
        pot_store4(ws + ((size_t)bid * 16 + l) * 12, P);
}

// ---------- Kernel 2: tail.  35 blocks x 512 threads.
// Every block redundantly: load 32 pots, 5 composes (3r), shuffle final ->
// LDS blob; then writes out[bid*512 + tid].  Deterministic, race-free. ----
__global__ __launch_bounds__(512)
void hmm_tail(const float* __restrict__ bias_scales,
              const float* __restrict__ obs_noise_p,
              const float* __restrict__ ws,
              float* __restrict__ out)
{
    __shared__ float pool[2][8][16][13];
    __shared__ __align__(16) float cbuf[32 * GSTRIDE];
    __shared__ float sTi[8][8];
    __shared__ float sA[4];
    __shared__ float sLL;
    const int tid = (int)threadIdx.x;
    const int l = tid & 63, w = tid >> 6;
    const int i = (l >> 2) & 3, j = l & 3, gb = l & 48, g = (l >> 4) & 3;
    const int gid = w * 4 + g;
    float* gl = &cbuf[(size_t)gid * GSTRIDE];

    // hoisted input-only constants; f64 logs overlap the pot loads
    const double sg2d = (double)obs_noise_p[0] * (double)obs_noise_p[0];
    const double a00 = (double)bias_scales[0];
    const double a01 = (double)bias_scales[1];
    const double Td = 2048.0;
    const double c0d = sg2d/a00, c1d = sg2d/a01;
    const double llconst = -31.0*(Td*(L2PI + log(sg2d)) + log((c0d+Td)/c0d))
                           -31.0*(Td*(L2PI + log(sg2d)) + log((c1d+Td)/c1d))
                           -2.0*Td*log(32.0);
    const float gconst = (float)(-4.0*L2PI + 2.0*log(32.0) - log(a00) - log(a01));

    LP P = pot_load4(ws + ((size_t)gid * 16 + (l & 15)) * 12);
    #pragma unroll 1
    for (int op = 0; op < 5; ++op) {
        LP A, Bp;
        if (op < 2) {
            const int m = 16 << op;
            LP O = fetchx(P, m);
            const bool up = (l & m) != 0;
            A  = csel(up, O, P);
            Bp = csel(up, P, O);
        } else {
            const int s = 1 << (op - 2);
            const int buf = (op - 2) & 1;
            if (l < 16) pot_store(&pool[buf][w][l][0], P);
            __syncthreads();
            LP O = pot_load(&pool[buf][w ^ s][l & 15][0]);
            const bool up = (w & s) != 0;
            A  = csel(up, O, P);
            Bp = csel(up, P, O);
        }
        P = compose_3r(A, Bp, gl, i, j);
    }

    // ---------- final stage on wave 0 (R4/R9 shuffle version) ----------
    if (w == 0) {
        const float a0i = (float)((i & 1) ? a01 : a00);
        P.jFF += (i == j) ? 1.0f : 0.0f;
        P.jBB += (i == j) ? 32.0f / a0i : 0.0f;
        P.g   += gconst;
        float dm = P.dm, de = P.de;
        // marginalize z0: adjugate inverse of jFF
        float S = P.jFF;
        const int r0 = (j == 0) ? 1 : 0;
        const int r1 = (j <= 1) ? 2 : 1;
        const int r2 = (j <= 2) ? 3 : 2;
        const int c0 = (i == 0) ? 1 : 0;
        const int c1 = (i <= 1) ? 2 : 1;
        const int c2 = (i <= 2) ? 3 : 2;
        float m00 = shf(S, gb + 4*r0 + c0), m01 = shf(S, gb + 4*r0 + c1), m02 = shf(S, gb + 4*r0 + c2);
        float m10 = shf(S, gb + 4*r1 + c0), m11 = shf(S, gb + 4*r1 + c1), m12 = shf(S, gb + 4*r1 + c2);
        float m20 = shf(S, gb + 4*r2 + c0), m21 = shf(S, gb + 4*r2 + c1), m22 = shf(S, gb + 4*r2 + c2);
        float d0 = fmaf(m11, m22, -m12*m21);
        float d1 = fmaf(m10, m22, -m12*m20);
        float d2 = fmaf(m10, m21, -m11*m20);
        float det3 = m00*d0 - m01*d1 + m02*d2;
        float adj = (((i + j) & 1) ? -det3 : det3);
        float sji = shf(S, gb + 4*j + i);
        float tdet = sji * adj;
        tdet += sx(tdet, 4); tdet += sx(tdet, 8);
        float det = tdet;
        dm *= det; { int ex; dm = frexpf(dm, &ex); de += (float)ex; }
        const float Si = adj * (1.0f / det);
        float sr[4], fr[4], fT[4], bc[4], bT[4], hfc[4];
        #pragma unroll
        for (int r = 0; r < 4; ++r) {
            sr[r]  = shf(Si, gb + 4*i + r);
            fr[r]  = shf(P.jFL, gb + 4*r + i);
            fT[r]  = shf(P.jFL, gb + 4*r + j);
            bc[r]  = shf(P.jFB, gb + 4*r + i);
            bT[r]  = shf(P.jFB, gb + 4*r + j);
            hfc[r] = shf(P.hF, gb + 5*r);
        }
        float YL = 0.0f, YB = 0.0f, yFi = 0.0f;
        #pragma unroll
        for (int r = 0; r < 4; ++r) {
            YL  = fmaf(sr[r], fT[r], YL);
            YB  = fmaf(sr[r], bT[r], YB);
            yFi = fmaf(sr[r], hfc[r], yFi);
        }
        float ylc[4], ybc[4], yfc[4];
        #pragma unroll
        for (int r = 0; r < 4; ++r) {
            ylc[r] = shf(YL, gb + 4*r + j);
            ybc[r] = shf(YB, gb + 4*r + j);
            yfc[r] = shf(yFi, gb + 5*r);
        }
        float s1 = 0.0f, s2 = 0.0f, s3 = 0.0f, sh1 = 0.0f, sh2 = 0.0f, qF = 0.0f;
        #pragma unroll
        for (int r = 0; r < 4; ++r) {
            s1  = fmaf(fr[r], ylc[r], s1);
            s2  = fmaf(fr[r], ybc[r], s2);
            s3  = fmaf(bc[r], ybc[r], s3);
            sh1 = fmaf(fT[r], yfc[r], sh1);
            sh2 = fmaf(bT[r], yfc[r], sh2);
            qF  = fmaf(hfc[r], yfc[r], qF);
        }
        float J8ss = P.jLL - s1;
        float J8sb = P.jLB - s2;
        float J8bb = P.jBB - s3;
        float h8s  = P.hL - sh1;
        float h8b  = P.hB - sh2;
        float g8   = P.g + 2.0f*(float)L2PI + 0.5f*qF;

        // 8x8 stage across all 64 lanes: lane = (I,J)
        const int I = l >> 3, J = l & 7, i4 = I & 3, j4 = J & 3;
        float ss  = shf(J8ss, 4*i4 + j4);
        float sb  = shf(J8sb, 4*i4 + j4);
        float sbT = shf(J8sb, 4*j4 + i4);
        float bb  = shf(J8bb, 4*i4 + j4);
        float A8 = (I < 4) ? ((J < 4) ? ss : sb) : ((J < 4) ? sbT : bb);
        const float J8sav = A8;
        float h8v = (J < 4) ? shf(h8s, j4) : shf(h8b, j4);
        float h8r = (I < 4) ? shf(h8s, i4) : shf(h8b, i4);
        float K8 = (I == J) ? 1.0f : 0.0f;
        #pragma unroll 1
        for (int p = 0; p < 8; ++p) {
            float piv = shf(A8, 9*p);
            dm *= piv; { int ex; dm = frexpf(dm, &ex); de += (float)ex; }
            float ip = 1.0f / piv;
            float Ap = shf(A8, 8*p + J) * ip;
            float Kp = shf(K8, 8*p + J) * ip;
            float f  = shf(A8, 8*I + p);
            bool isp = (I == p);
            A8 = isp ? A8 * ip : fmaf(-f, Ap, A8);
            K8 = isp ? K8 * ip : fmaf(-f, Kp, K8);
        }
        float tq = h8r * K8 * h8v;
        tq += sx(tq,1); tq += sx(tq,2); tq += sx(tq,4);
        tq += sx(tq,8); tq += sx(tq,16); tq += sx(tq,32);

        double ll = (double)g8 + 4.0*L2PI
                    - 0.5*(log((double)dm) + (double)de*LN2) + 0.5*(double)tq;
        ll += llconst;

        const float i32 = 1.0f/32.0f, irn = 0.176776695296637f;
        int a = (I >= 4) ? I - 4 : I + 4;
        int b = (J >= 4) ? J - 4 : J + 4;
        float scale = (I >= 4 && J >= 4) ? i32 : (((I >= 4) != (J >= 4)) ? irn : 1.0f);
        sTi[a][b] = J8sav * scale;
        if (l < 4) {
            double a0k = (l & 1) ? a01 : a00;
            sA[l] = (float)(a0k*sg2d/(sg2d + Td*a0k));
        }
        if (l == 0) sLL = (float)ll;
    }
    __syncthreads();

    // ---------- sliced expand: this block writes out[bid*512 + tid] ----------
    const float inv32 = 1.0f/32.0f;
    const float invrn = 0.176776695296637f;
    const int total = 1 + 132*132;
    const int idx = (int)blockIdx.x * 512 + tid;
    if (idx < total) {
        float v;
        if (idx == 0) {
            v = sLL;
        } else {
            int el = idx - 1;
            int r = el / 132;
            int cc = el - 132*r;
            if (r < 128) {
                int ki = ((r >> 6) << 1) | (r & 1);
                if (cc < 128) {
                    int kj = ((cc >> 6) << 1) | (cc & 1);
                    v = sTi[ki][kj] * inv32;
                    if (ki == kj) {
                        float ia = 1.0f / sA[ki];
                        v -= ia * inv32;
                        if (r == cc) v += ia;
                    }
                } else {
                    v = sTi[ki][cc - 124] * invrn;
                }
            } else {
                if (cc < 128) {
                    int kj = ((cc >> 6) << 1) | (cc & 1);
                    v = sTi[kj][r - 124] * invrn;
                } else {
                    v = sTi[r - 124][cc - 124];
                }
            }
        }
        out[idx] = v;
    }
}

extern "C" void kernel_launch(void* const* d_in, const int* in_sizes, int n_in,
                              void* d_out, int out_size, void* d_ws, size_t ws_size,
                              hipStream_t stream) {
    (void)in_sizes; (void)n_in; (void)out_size; (void)ws_size;
    const float* track       = (const float*)d_in[0];
    const float* bias_scales = (const float*)d_in[1];
    const float* obs_noise   = (const float*)d_in[2];
    const float* trans_noise = (const float*)d_in[3];
    float* out = (float*)d_out;
    float* ws  = (float*)d_ws;   // pots 24 KB
    hipLaunchKernelGGL(hmm_produce, dim3(32), dim3(512), 0, stream,
                       track, obs_noise, trans_noise, ws);
    hipLaunchKernelGGL(hmm_tail, dim3(35), dim3(512), 0, stream,
                       bias_scales, obs_noise, ws, out);
}